// Round 11
// baseline (304.088 us; speedup 1.0000x reference)
//
#include <hip/hip_runtime.h>
#include <hip/hip_bf16.h>

#define H 128
#define IN_DIM 30
#define LDSP 136  // padded row stride (ushorts) for staged activations
#define LDSP1 72  // padded row stride for lin1 strips (K=64)

typedef __attribute__((ext_vector_type(8))) short bf16x8;
typedef __attribute__((ext_vector_type(8))) unsigned short u16x8;
typedef __attribute__((ext_vector_type(4))) float f32x4;

__device__ inline unsigned short f2bf(float f){
  unsigned int u = __builtin_bit_cast(unsigned int, f);
  unsigned int r = u + 0x7FFF + ((u >> 16) & 1);
  return (unsigned short)(r >> 16);
}
__device__ inline float bf2f(unsigned short b){
  unsigned int u = ((unsigned int)b) << 16;
  return __builtin_bit_cast(float, u);
}
__device__ inline bf16x8 ldfrag(const unsigned short* p){
  return *(const bf16x8*)p;
}

// ---------------- CSR build (XCD-partitioned: block b owns node range of partition b&7) ----------------
__global__ void k_count(const int* __restrict__ col, int* __restrict__ counts,
                        int E, int npp){
  int part = blockIdx.x & 7;
  int inst = blockIdx.x >> 3;
  int ninst = gridDim.x >> 3;
  int lo = part*npp, hi = lo + npp;
  for (int e = inst*blockDim.x + threadIdx.x; e < E; e += ninst*blockDim.x){
    int c = col[e];
    if (c >= lo && c < hi) atomicAdd(&counts[c], 1);
  }
}

__global__ void k_scanA(const int* __restrict__ counts, int* __restrict__ offsets,
                        int* __restrict__ bsum, int n){
  __shared__ int buf[256];
  int i = blockIdx.x*256 + threadIdx.x;
  int v = (i < n) ? counts[i] : 0;
  buf[threadIdx.x] = v; __syncthreads();
  for (int off = 1; off < 256; off <<= 1){
    int t = (threadIdx.x >= off) ? buf[threadIdx.x - off] : 0;
    __syncthreads();
    buf[threadIdx.x] += t;
    __syncthreads();
  }
  if (i < n) offsets[i] = buf[threadIdx.x] - v;
  if (threadIdx.x == 255) bsum[blockIdx.x] = buf[255];
}

__global__ void k_scanB(int* __restrict__ bsum, int nb){
  __shared__ int buf[256];
  int v = (threadIdx.x < nb) ? bsum[threadIdx.x] : 0;
  buf[threadIdx.x] = v; __syncthreads();
  for (int off = 1; off < 256; off <<= 1){
    int t = (threadIdx.x >= off) ? buf[threadIdx.x - off] : 0;
    __syncthreads();
    buf[threadIdx.x] += t;
    __syncthreads();
  }
  if (threadIdx.x < nb) bsum[threadIdx.x] = buf[threadIdx.x] - v;
}

__global__ void k_scanC(int* __restrict__ offsets, int* __restrict__ cursor,
                        const int* __restrict__ bsum, int n){
  int i = blockIdx.x*256 + threadIdx.x;
  if (i < n){ int o = offsets[i] + bsum[blockIdx.x]; offsets[i] = o; cursor[i] = o; }
}

__global__ void k_scatter(const int* __restrict__ ei, int* __restrict__ cursor,
                          int* __restrict__ csr, int E, int npp){
  int part = blockIdx.x & 7;
  int inst = blockIdx.x >> 3;
  int ninst = gridDim.x >> 3;
  int lo = part*npp, hi = lo + npp;
  for (int e = inst*blockDim.x + threadIdx.x; e < E; e += ninst*blockDim.x){
    int c = ei[E + e];
    if (c >= lo && c < hi){
      int p = atomicAdd(&cursor[c], 1);
      csr[p] = ei[e];
    }
  }
}

// ---------------- weight conversion to bf16 ----------------
// V2 layout [160][128]: rows 0..63 = Wf1 P-part, 64..127 = Wf1 Q-part, 128..159 = Wd1
// W1c layout [128][64]: cols 0..29 = W1l, 32..61 = W1r, rest 0
__global__ void k_wconv(const float* __restrict__ W2l, const float* __restrict__ W2r,
                        const float* __restrict__ Wih, const float* __restrict__ Whh,
                        const float* __restrict__ Wf1, const float* __restrict__ Wd1,
                        const float* __restrict__ W1l, const float* __restrict__ W1r,
                        unsigned short* __restrict__ W2l_bf, unsigned short* __restrict__ W2r_bf,
                        unsigned short* __restrict__ Wih_bf, unsigned short* __restrict__ Whh_bf,
                        unsigned short* __restrict__ V2_bf, unsigned short* __restrict__ W1c_bf){
  int stride = gridDim.x*blockDim.x;
  for (int i = blockIdx.x*blockDim.x + threadIdx.x; i < 49152; i += stride){
    if (i < 8192){
      int c = i >> 6, k = i & 63;
      float v = 0.f;
      if (k < IN_DIM)                      v = W1l[c*IN_DIM + k];
      else if (k >= 32 && k < 32 + IN_DIM) v = W1r[c*IN_DIM + (k - 32)];
      W1c_bf[i] = f2bf(v);
    }
    if (i < 16384){
      W2l_bf[i] = f2bf(W2l[i]);
      W2r_bf[i] = f2bf(W2r[i]);
    }
    if (i < 20480){
      int j = i >> 7, k = i & 127;
      float v;
      if (j < 64)        v = Wf1[j*260 + k];
      else if (j < 128)  v = Wf1[(j-64)*260 + 128 + k];
      else               v = Wd1[(j-128)*128 + k];
      V2_bf[i] = f2bf(v);
    }
    Wih_bf[i] = f2bf(Wih[i]);
    Whh_bf[i] = f2bf(Whh[i]);
  }
}

// ---------------- x f32 [N][30] -> bf16 [N][32] (padded) ----------------
__global__ void k_xconv(const float* __restrict__ x, unsigned short* __restrict__ xbf, int total){
  int stride = gridDim.x*blockDim.x;
  for (int i = blockIdx.x*blockDim.x + threadIdx.x; i < total; i += stride){
    int d = i >> 5, c = i & 31;
    xbf[i] = (c < IN_DIM) ? f2bf(x[(size_t)d*IN_DIM + c]) : (unsigned short)0;
  }
}

// ---------------- aggx: mean of x_bf (32-col) rows -> bf16 [N][32] ----------------
__global__ __launch_bounds__(256) void k_aggx(
    const unsigned short* __restrict__ xbf, const int* __restrict__ csr,
    const int* __restrict__ offsets, const int* __restrict__ counts,
    unsigned short* __restrict__ aggxbf, int N)
{
  int t = blockIdx.x*blockDim.x + threadIdx.x;
  int gw = t >> 6, lane = t & 63;
  int nw = (gridDim.x*blockDim.x) >> 6;
  int half = lane >> 5, c = lane & 31;
  for (int d = gw; d < N; d += nw){
    int base = offsets[d], cnt = counts[d];
    float s0 = 0.f, s1 = 0.f;
    int i = half;
    for (; i + 2 < cnt; i += 4){
      int sr0 = csr[base + i];
      int sr1 = csr[base + i + 2];
      s0 += bf2f(xbf[(size_t)sr0*32 + c]);
      s1 += bf2f(xbf[(size_t)sr1*32 + c]);
    }
    for (; i < cnt; i += 2){
      int sr = csr[base + i];
      s0 += bf2f(xbf[(size_t)sr*32 + c]);
    }
    float s = s0 + s1;
    s += __shfl_xor(s, 32);
    if (lane < 32){
      float inv = 1.f / (float)(cnt > 0 ? cnt : 1);
      aggxbf[(size_t)d*32 + c] = f2bf(s*inv);
    }
  }
}

// ---------------- lin1 via MFMA strips: x1 = relu([agg|x] @ W1c.T + b1l) ----------------
__global__ __launch_bounds__(512) void k_lin1m(
    const unsigned short* __restrict__ aggxbf, const unsigned short* __restrict__ xbf,
    const unsigned short* __restrict__ W1c_bf, const float* __restrict__ b1l,
    unsigned short* __restrict__ x1bf, int N)
{
  __shared__ unsigned short sA[128*LDSP1];
  int tid = threadIdx.x;
  int wid = tid >> 6, l = tid & 63, m16 = l & 15, g4 = l >> 4;
  int col = wid*16 + m16;
  bf16x8 w1[2];
  #pragma unroll
  for (int kb = 0; kb < 2; kb++)
    w1[kb] = ldfrag(W1c_bf + (size_t)col*64 + kb*32 + g4*8);
  float bc = b1l[col];
  int nstrips = (N + 127) >> 7;
  for (int s = blockIdx.x; s < nstrips; s += gridDim.x){
    int base = s << 7;
    __syncthreads();
    for (int i = tid; i < 1024; i += 512){
      int row = i >> 3, c8 = (i & 7) << 3;
      int gr = min(base + row, N-1);
      u16x8 v;
      if (c8 < 32) v = *(const u16x8*)&aggxbf[(size_t)gr*32 + c8];
      else         v = *(const u16x8*)&xbf[(size_t)gr*32 + (c8 - 32)];
      *(u16x8*)&sA[row*LDSP1 + c8] = v;
    }
    __syncthreads();
    #pragma unroll 1
    for (int rt = 0; rt < 8; rt++){
      int rb = rt*16;
      f32x4 acc = {bc, bc, bc, bc};
      #pragma unroll
      for (int kb = 0; kb < 2; kb++){
        bf16x8 a = *(const bf16x8*)&sA[(rb + m16)*LDSP1 + kb*32 + g4*8];
        acc = __builtin_amdgcn_mfma_f32_16x16x32_bf16(a, w1[kb], acc, 0, 0, 0);
      }
      #pragma unroll
      for (int j = 0; j < 4; j++){
        int row = base + rb + g4*4 + j;
        if (row < N)
          x1bf[(size_t)row*H + col] = f2bf(fmaxf(acc[j], 0.f));
      }
    }
  }
}

// ---------------- agg2 ----------------
__global__ __launch_bounds__(256) void k_agg2(
    const unsigned short* __restrict__ x1bf, const int* __restrict__ csr,
    const int* __restrict__ offsets, const int* __restrict__ counts,
    unsigned short* __restrict__ agg2bf, int N)
{
  int t = blockIdx.x*blockDim.x + threadIdx.x;
  int gw = t >> 6, lane = t & 63;
  int nw = (gridDim.x*blockDim.x) >> 6;
  const unsigned int* x1u = (const unsigned int*)x1bf;
  unsigned int* agu = (unsigned int*)agg2bf;
  for (int d = gw; d < N; d += nw){
    int base = offsets[d], cnt = counts[d];
    float a0 = 0.f, a1 = 0.f;
    int i = 0;
    for (; i + 3 < cnt; i += 4){
      int s0 = csr[base + i],     s1 = csr[base + i + 1];
      int s2 = csr[base + i + 2], s3 = csr[base + i + 3];
      unsigned int v0 = x1u[(size_t)s0*64 + lane];
      unsigned int v1 = x1u[(size_t)s1*64 + lane];
      unsigned int v2 = x1u[(size_t)s2*64 + lane];
      unsigned int v3 = x1u[(size_t)s3*64 + lane];
      a0 += bf2f((unsigned short)(v0 & 0xffff)) + bf2f((unsigned short)(v1 & 0xffff))
          + bf2f((unsigned short)(v2 & 0xffff)) + bf2f((unsigned short)(v3 & 0xffff));
      a1 += bf2f((unsigned short)(v0 >> 16)) + bf2f((unsigned short)(v1 >> 16))
          + bf2f((unsigned short)(v2 >> 16)) + bf2f((unsigned short)(v3 >> 16));
    }
    for (; i < cnt; i++){
      unsigned int v = x1u[(size_t)csr[base + i]*64 + lane];
      a0 += bf2f((unsigned short)(v & 0xffff));
      a1 += bf2f((unsigned short)(v >> 16));
    }
    float inv = 1.f / (float)(cnt > 0 ? cnt : 1);
    unsigned int o = (unsigned int)f2bf(a0*inv) | ((unsigned int)f2bf(a1*inv) << 16);
    agu[(size_t)d*64 + lane] = o;
  }
}

// ============ strip GEMM kernels: 512 thr, 128-row strips, LDS-staged A ============

// ---------------- SAGE2: x2 = relu(agg2@W2l.T + b2l + x1@W2r.T) ----------------
__global__ __launch_bounds__(512) void k_dual2(
    const unsigned short* __restrict__ Abf, const unsigned short* __restrict__ Bbf,
    const unsigned short* __restrict__ Wa, const unsigned short* __restrict__ Wb,
    const float* __restrict__ bias, unsigned short* __restrict__ outbf, int N)
{
  __shared__ unsigned short sA[128*LDSP];
  __shared__ unsigned short sB[128*LDSP];
  int tid = threadIdx.x;
  int wid = tid >> 6, l = tid & 63, m16 = l & 15, g4 = l >> 4;
  int col = wid*16 + m16;
  bf16x8 wa[4], wb[4];
  #pragma unroll
  for (int kb = 0; kb < 4; kb++){
    wa[kb] = ldfrag(Wa + (size_t)col*H + kb*32 + g4*8);
    wb[kb] = ldfrag(Wb + (size_t)col*H + kb*32 + g4*8);
  }
  float bc = bias[col];
  int nstrips = (N + 127) >> 7;
  for (int s = blockIdx.x; s < nstrips; s += gridDim.x){
    int base = s << 7;
    __syncthreads();
    for (int c = tid; c < 4096; c += 512){
      int mat = c >> 11, cc = c & 2047;
      int row = cc >> 4, co = cc & 15;
      int gr = min(base + row, N-1);
      u16x8 v = *(const u16x8*)((mat ? Bbf : Abf) + (size_t)gr*H + co*8);
      *(u16x8*)&((mat ? sB : sA)[row*LDSP + co*8]) = v;
    }
    __syncthreads();
    #pragma unroll 1
    for (int rt = 0; rt < 8; rt++){
      int rb = rt*16;
      f32x4 acc = {bc, bc, bc, bc};
      #pragma unroll
      for (int kb = 0; kb < 4; kb++){
        bf16x8 a = *(const bf16x8*)&sA[(rb + m16)*LDSP + kb*32 + g4*8];
        acc = __builtin_amdgcn_mfma_f32_16x16x32_bf16(a, wa[kb], acc, 0, 0, 0);
        bf16x8 b = *(const bf16x8*)&sB[(rb + m16)*LDSP + kb*32 + g4*8];
        acc = __builtin_amdgcn_mfma_f32_16x16x32_bf16(b, wb[kb], acc, 0, 0, 0);
      }
      #pragma unroll
      for (int j = 0; j < 4; j++){
        int row = base + rb + g4*4 + j;
        if (row < N)
          outbf[(size_t)row*H + col] = f2bf(fmaxf(acc[j], 0.f));
      }
    }
  }
}

// ---------------- fused GRU (stages h f32 -> bf16 inline) ----------------
__global__ __launch_bounds__(512) void k_gru2(
    const unsigned short* __restrict__ x2bf, const float* __restrict__ h,
    const unsigned short* __restrict__ Wih_bf, const unsigned short* __restrict__ Whh_bf,
    const float* __restrict__ bih, const float* __restrict__ bhh,
    float* __restrict__ hnew, unsigned short* __restrict__ hnewbf, int N)
{
  __shared__ unsigned short sX[128*LDSP];
  __shared__ unsigned short sH[128*LDSP];
  int tid = threadIdx.x;
  int wid = tid >> 6, l = tid & 63, m16 = l & 15, g4 = l >> 4;
  int col = wid*16 + m16;
  bf16x8 wih[3][4], whh[3][4];
  #pragma unroll
  for (int g = 0; g < 3; g++){
    #pragma unroll
    for (int kb = 0; kb < 4; kb++){
      wih[g][kb] = ldfrag(Wih_bf + (size_t)(g*H + col)*H + kb*32 + g4*8);
      whh[g][kb] = ldfrag(Whh_bf + (size_t)(g*H + col)*H + kb*32 + g4*8);
    }
  }
  float bir = bih[col],       bhr = bhh[col];
  float biz = bih[H + col],   bhz = bhh[H + col];
  float bin = bih[2*H + col], bhn = bhh[2*H + col];
  int nstrips = (N + 127) >> 7;
  for (int s = blockIdx.x; s < nstrips; s += gridDim.x){
    int base = s << 7;
    __syncthreads();
    for (int c = tid; c < 4096; c += 512){
      int mat = c >> 11, cc = c & 2047;
      int row = cc >> 4, co = cc & 15;
      int gr = min(base + row, N-1);
      if (mat == 0){
        u16x8 v = *(const u16x8*)(x2bf + (size_t)gr*H + co*8);
        *(u16x8*)&sX[row*LDSP + co*8] = v;
      } else {
        float4 f0 = *(const float4*)(h + (size_t)gr*H + co*8);
        float4 f1 = *(const float4*)(h + (size_t)gr*H + co*8 + 4);
        u16x8 v;
        v[0] = f2bf(f0.x); v[1] = f2bf(f0.y); v[2] = f2bf(f0.z); v[3] = f2bf(f0.w);
        v[4] = f2bf(f1.x); v[5] = f2bf(f1.y); v[6] = f2bf(f1.z); v[7] = f2bf(f1.w);
        *(u16x8*)&sH[row*LDSP + co*8] = v;
      }
    }
    __syncthreads();
    #pragma unroll 1
    for (int rt = 0; rt < 8; rt++){
      int rb = rt*16;
      bf16x8 aX[4], aH[4];
      #pragma unroll
      for (int kb = 0; kb < 4; kb++){
        aX[kb] = *(const bf16x8*)&sX[(rb + m16)*LDSP + kb*32 + g4*8];
        aH[kb] = *(const bf16x8*)&sH[(rb + m16)*LDSP + kb*32 + g4*8];
      }
      f32x4 aRi = {bir,bir,bir,bir}, aRh = {bhr,bhr,bhr,bhr};
      f32x4 aZi = {biz,biz,biz,biz}, aZh = {bhz,bhz,bhz,bhz};
      f32x4 aNi = {bin,bin,bin,bin}, aNh = {bhn,bhn,bhn,bhn};
      #pragma unroll
      for (int kb = 0; kb < 4; kb++){
        aRi = __builtin_amdgcn_mfma_f32_16x16x32_bf16(aX[kb], wih[0][kb], aRi, 0,0,0);
        aRh = __builtin_amdgcn_mfma_f32_16x16x32_bf16(aH[kb], whh[0][kb], aRh, 0,0,0);
        aZi = __builtin_amdgcn_mfma_f32_16x16x32_bf16(aX[kb], wih[1][kb], aZi, 0,0,0);
        aZh = __builtin_amdgcn_mfma_f32_16x16x32_bf16(aH[kb], whh[1][kb], aZh, 0,0,0);
        aNi = __builtin_amdgcn_mfma_f32_16x16x32_bf16(aX[kb], wih[2][kb], aNi, 0,0,0);
        aNh = __builtin_amdgcn_mfma_f32_16x16x32_bf16(aH[kb], whh[2][kb], aNh, 0,0,0);
      }
      #pragma unroll
      for (int j = 0; j < 4; j++){
        int row = base + rb + g4*4 + j;
        if (row < N){
          float r = 1.f / (1.f + expf(-(aRi[j] + aRh[j])));
          float z = 1.f / (1.f + expf(-(aZi[j] + aZh[j])));
          float nn = tanhf(aNi[j] + r*aNh[j]);
          float hv = bf2f(sH[(rb + g4*4 + j)*LDSP + col]);
          float o = (1.f - z)*nn + z*hv;
          hnew[(size_t)row*H + col] = o;
          hnewbf[(size_t)row*H + col] = f2bf(o);
        }
      }
    }
  }
}

// ---------------- proj: PQ (bf16, cols 0..127) and D1 (relu f32, V2 rows 128..159) ----------------
__global__ __launch_bounds__(512) void k_proj2(
    const unsigned short* __restrict__ hnewbf, const unsigned short* __restrict__ V2_bf,
    const float* __restrict__ bd1,
    unsigned short* __restrict__ PQbf, float* __restrict__ D1, int N)
{
  __shared__ unsigned short sHn[128*LDSP];
  int tid = threadIdx.x;
  int wid = tid >> 6, l = tid & 63, m16 = l & 15, g4 = l >> 4;
  int col = wid*16 + m16;
  bf16x8 v1[4], v2[4];
  #pragma unroll
  for (int kb = 0; kb < 4; kb++)
    v1[kb] = ldfrag(V2_bf + (size_t)col*H + kb*32 + g4*8);
  int dc = wid*16 + m16;
  float bdv = 0.f;
  if (wid < 2){
    #pragma unroll
    for (int kb = 0; kb < 4; kb++)
      v2[kb] = ldfrag(V2_bf + (size_t)(128 + dc)*H + kb*32 + g4*8);
    bdv = bd1[dc];
  }
  int nstrips = (N + 127) >> 7;
  for (int s = blockIdx.x; s < nstrips; s += gridDim.x){
    int base = s << 7;
    __syncthreads();
    for (int c = tid; c < 2048; c += 512){
      int row = c >> 4, co = c & 15;
      int gr = min(base + row, N-1);
      u16x8 v = *(const u16x8*)(hnewbf + (size_t)gr*H + co*8);
      *(u16x8*)&(sHn[row*LDSP + co*8]) = v;
    }
    __syncthreads();
    #pragma unroll 1
    for (int rt = 0; rt < 8; rt++){
      int rb = rt*16;
      bf16x8 aH[4];
      #pragma unroll
      for (int kb = 0; kb < 4; kb++)
        aH[kb] = *(const bf16x8*)&sHn[(rb + m16)*LDSP + kb*32 + g4*8];
      f32x4 acc = {0.f, 0.f, 0.f, 0.f};
      #pragma unroll
      for (int kb = 0; kb < 4; kb++)
        acc = __builtin_amdgcn_mfma_f32_16x16x32_bf16(aH[kb], v1[kb], acc, 0, 0, 0);
      #pragma unroll
      for (int j = 0; j < 4; j++){
        int row = base + rb + g4*4 + j;
        if (row < N)
          PQbf[(size_t)row*H + col] = f2bf(acc[j]);
      }
      if (wid < 2){
        f32x4 acc2 = {0.f, 0.f, 0.f, 0.f};
        #pragma unroll
        for (int kb = 0; kb < 4; kb++)
          acc2 = __builtin_amdgcn_mfma_f32_16x16x32_bf16(aH[kb], v2[kb], acc2, 0, 0, 0);
        #pragma unroll
        for (int j = 0; j < 4; j++){
          int row = base + rb + g4*4 + j;
          if (row < N)
            D1[(size_t)row*32 + dc] = fmaxf(acc2[j] + bdv, 0.f);
        }
      }
    }
  }
}

// ---------------- disp from D1: 32-lane group per node ----------------
__global__ __launch_bounds__(256) void k_disp2(
    const float* __restrict__ D1, const float* __restrict__ Wd2,
    const float* __restrict__ bd2, float* __restrict__ disp, int N)
{
  int t = blockIdx.x*blockDim.x + threadIdx.x;
  int gh = t >> 5, sub = t & 31;
  int nh = (gridDim.x*blockDim.x) >> 5;
  float w0 = Wd2[sub], w1 = Wd2[32 + sub], w2 = Wd2[64 + sub];
  float bo = (sub < 3) ? bd2[sub] : 0.f;
  for (int d = gh; d < N; d += nh){
    float v = D1[(size_t)d*32 + sub];
    float v0 = v*w0, v1 = v*w1, v2 = v*w2;
    #pragma unroll
    for (int off = 1; off < 32; off <<= 1){
      v0 += __shfl_xor(v0, off, 32);
      v1 += __shfl_xor(v1, off, 32);
      v2 += __shfl_xor(v2, off, 32);
    }
    if (sub < 3) disp[(size_t)d*3 + sub] = (sub == 0 ? v0 : (sub == 1 ? v1 : v2)) + bo;
  }
}

// ---------------- force decoder: MFMA over 16-edge tiles, 5-stage pipelined gathers ----------------
__global__ __launch_bounds__(256) void k_force(
    const int* __restrict__ ei, const float* __restrict__ ea,
    const unsigned short* __restrict__ PQbf,
    const float* __restrict__ Wf1, const float* __restrict__ bf1,
    const float* __restrict__ Wf2, const float* __restrict__ bf2,
    float* __restrict__ out, int E)
{
  int l = threadIdx.x & 63;
  int r = l & 15, g = l >> 4;
  float4 wc0[8], wc1[8];
  float b1r0[8], b1r1[8];
  bf16x8 bfr0, bfr1;
  float bo = (r < 3) ? bf2[r] : 0.f;
  #pragma unroll
  for (int j = 0; j < 8; j++){
    int k0 = g*8 + j, k1 = 32 + g*8 + j;
    wc0[j] = *(const float4*)&Wf1[k0*260 + 256];
    wc1[j] = *(const float4*)&Wf1[k1*260 + 256];
    b1r0[j] = bf1[k0];
    b1r1[j] = bf1[k1];
    bfr0[j] = (r < 3) ? (short)f2bf(Wf2[r*64 + k0]) : (short)0;
    bfr1[j] = (r < 3) ? (short)f2bf(Wf2[r*64 + k1]) : (short)0;
  }
  int nt = (E + 15) >> 4;
  int stride = gridDim.x*4;
  int tA = blockIdx.x*4 + (threadIdx.x >> 6);
  if (tA >= nt) return;
  int tB = tA + stride, tC = tB + stride, tD = tC + stride;

  // idx + ea for stages A, B, C
  int pcA = min(tA*16 + r, E-1);
  int sA_ = ei[pcA], dA_ = ei[E + pcA];
  float4 aA = *(const float4*)&ea[(size_t)pcA*4];
  int sB_ = 0, dB_ = 0; float4 aB = {0.f,0.f,0.f,0.f};
  if (tB < nt){
    int pc = min(tB*16 + r, E-1);
    sB_ = ei[pc]; dB_ = ei[E + pc];
    aB = *(const float4*)&ea[(size_t)pc*4];
  }
  int sC_ = 0, dC_ = 0; float4 aC = {0.f,0.f,0.f,0.f};
  if (tC < nt){
    int pc = min(tC*16 + r, E-1);
    sC_ = ei[pc]; dC_ = ei[E + pc];
    aC = *(const float4*)&ea[(size_t)pc*4];
  }
  // PQ gathers for A and B
  u16x8 pA0 = *(const u16x8*)&PQbf[(size_t)sA_*H + g*8];
  u16x8 pA1 = *(const u16x8*)&PQbf[(size_t)sA_*H + 32 + g*8];
  u16x8 qA0 = *(const u16x8*)&PQbf[(size_t)dA_*H + 64 + g*8];
  u16x8 qA1 = *(const u16x8*)&PQbf[(size_t)dA_*H + 96 + g*8];
  u16x8 pB0 = {}, pB1 = {}, qB0 = {}, qB1 = {};
  if (tB < nt){
    pB0 = *(const u16x8*)&PQbf[(size_t)sB_*H + g*8];
    pB1 = *(const u16x8*)&PQbf[(size_t)sB_*H + 32 + g*8];
    qB0 = *(const u16x8*)&PQbf[(size_t)dB_*H + 64 + g*8];
    qB1 = *(const u16x8*)&PQbf[(size_t)dB_*H + 96 + g*8];
  }
  while (true){
    // issue PQ gathers for C
    u16x8 pC0 = {}, pC1 = {}, qC0 = {}, qC1 = {};
    if (tC < nt){
      pC0 = *(const u16x8*)&PQbf[(size_t)sC_*H + g*8];
      pC1 = *(const u16x8*)&PQbf[(size_t)sC_*H + 32 + g*8];
      qC0 = *(const u16x8*)&PQbf[(size_t)dC_*H + 64 + g*8];
      qC1 = *(const u16x8*)&PQbf[(size_t)dC_*H + 96 + g*8];
    }
    // idx + ea loads for D
    int sD_ = 0, dD_ = 0; float4 aD = {0.f,0.f,0.f,0.f};
    if (tD < nt){
      int pc = min(tD*16 + r, E-1);
      sD_ = ei[pc]; dD_ = ei[E + pc];
      aD = *(const float4*)&ea[(size_t)pc*4];
    }
    // compute stage A
    {
      bf16x8 af0, af1;
      #pragma unroll
      for (int j = 0; j < 8; j++){
        float pre0 = bf2f((unsigned short)pA0[j]) + bf2f((unsigned short)qA0[j]) + b1r0[j]
                   + aA.x*wc0[j].x + aA.y*wc0[j].y + aA.z*wc0[j].z + aA.w*wc0[j].w;
        af0[j] = (short)f2bf(fmaxf(pre0, 0.f));
        float pre1 = bf2f((unsigned short)pA1[j]) + bf2f((unsigned short)qA1[j]) + b1r1[j]
                   + aA.x*wc1[j].x + aA.y*wc1[j].y + aA.z*wc1[j].z + aA.w*wc1[j].w;
        af1[j] = (short)f2bf(fmaxf(pre1, 0.f));
      }
      f32x4 acc = {0.f, 0.f, 0.f, 0.f};
      acc = __builtin_amdgcn_mfma_f32_16x16x32_bf16(af0, bfr0, acc, 0, 0, 0);
      acc = __builtin_amdgcn_mfma_f32_16x16x32_bf16(af1, bfr1, acc, 0, 0, 0);
      if (r < 3){
        #pragma unroll
        for (int j = 0; j < 4; j++){
          int erow = tA*16 + g*4 + j;
          if (erow < E) out[(size_t)erow*3 + r] = acc[j] + bo;
        }
      }
    }
    if (tB >= nt) break;
    // rotate: A <- B <- C <- D
    tA = tB; tB = tC; tC = tD; tD += stride;
    aA = aB; pA0 = pB0; pA1 = pB1; qA0 = qB0; qA1 = qB1;
    aB = aC; pB0 = pC0; pB1 = pC1; qB0 = qC0; qB1 = qC1;
    sC_ = sD_; dC_ = dD_; aC = aD;
  }
}

extern "C" void kernel_launch(void* const* d_in, const int* in_sizes, int n_in,
                              void* d_out, int out_size, void* d_ws, size_t ws_size,
                              hipStream_t stream)
{
  const float* x   = (const float*)d_in[0];
  const int*   ei  = (const int*)d_in[1];
  const float* ea  = (const float*)d_in[2];
  const float* h   = (const float*)d_in[3];
  const float* W1l = (const float*)d_in[4];
  const float* b1l = (const float*)d_in[5];
  const float* W1r = (const float*)d_in[6];
  const float* W2l = (const float*)d_in[7];
  const float* b2l = (const float*)d_in[8];
  const float* W2r = (const float*)d_in[9];
  const float* Wih = (const float*)d_in[10];
  const float* Whh = (const float*)d_in[11];
  const float* bih = (const float*)d_in[12];
  const float* bhh = (const float*)d_in[13];
  const float* Wd1 = (const float*)d_in[14];
  const float* bd1 = (const float*)d_in[15];
  const float* Wd2 = (const float*)d_in[16];
  const float* bd2 = (const float*)d_in[17];
  const float* Wf1 = (const float*)d_in[18];
  const float* bf1 = (const float*)d_in[19];
  const float* Wf2 = (const float*)d_in[20];
  const float* bf2 = (const float*)d_in[21];

  int N = in_sizes[0] / IN_DIM;
  int E = in_sizes[1] / 2;
  int npp = (N + 7) / 8;  // nodes per XCD partition

  char* ws = (char*)d_ws;
  size_t off = 0;
  auto alloc = [&](size_t bytes) -> char* {
    char* p = ws + off;
    off = (off + bytes + 255) & ~(size_t)255;
    return p;
  };
  int* counts  = (int*)alloc((size_t)N*4);
  int* offsets = (int*)alloc((size_t)N*4);
  int* cursor  = (int*)alloc((size_t)N*4);
  int* bsum    = (int*)alloc(1024);
  int* csr     = (int*)alloc((size_t)E*4);
  // pool: aggxbf(uses 3.2MB of 6.4MB slot) | x1bf(12.8MB) | agg2bf(12.8MB);
  // reused post-GRU: PQbf (12.8MB) over aggx+x1bf slots; D1 (6.4MB) over agg2bf
  unsigned short* aggxbf = (unsigned short*)alloc((size_t)N*32*4);
  unsigned short* x1bf   = (unsigned short*)alloc((size_t)N*H*2);
  unsigned short* agg2bf = (unsigned short*)alloc((size_t)N*H*2);
  unsigned short* PQbf = (unsigned short*)aggxbf;
  float* D1            = (float*)agg2bf;
  unsigned short* x2bf   = (unsigned short*)alloc((size_t)N*H*2);
  unsigned short* hnewbf = (unsigned short*)alloc((size_t)N*H*2);
  unsigned short* xbf    = (unsigned short*)alloc((size_t)N*32*2);
  unsigned short* W2l_bf = (unsigned short*)alloc(16384*2);
  unsigned short* W2r_bf = (unsigned short*)alloc(16384*2);
  unsigned short* Wih_bf = (unsigned short*)alloc(49152*2);
  unsigned short* Whh_bf = (unsigned short*)alloc(49152*2);
  unsigned short* V2_bf  = (unsigned short*)alloc(20480*2);
  unsigned short* W1c_bf = (unsigned short*)alloc(8192*2);

  float* disp  = (float*)d_out;
  float* force = disp + (size_t)N*3;
  float* hnew  = force + (size_t)E*3;

  hipMemsetAsync(counts, 0, (size_t)N*4, stream);
  int nb = (N + 255) / 256;
  k_count  <<<2048, 256, 0, stream>>>(ei + E, counts, E, npp);
  k_scanA  <<<nb, 256, 0, stream>>>(counts, offsets, bsum, N);
  k_scanB  <<<1, 256, 0, stream>>>(bsum, nb);
  k_scanC  <<<nb, 256, 0, stream>>>(offsets, cursor, bsum, N);
  k_scatter<<<2048, 256, 0, stream>>>(ei, cursor, csr, E, npp);

  k_wconv  <<<192, 256, 0, stream>>>(W2l, W2r, Wih, Whh, Wf1, Wd1, W1l, W1r,
                                     W2l_bf, W2r_bf, Wih_bf, Whh_bf, V2_bf, W1c_bf);
  k_xconv  <<<1024, 256, 0, stream>>>(x, xbf, N*32);

  k_aggx   <<<4096, 256, 0, stream>>>(xbf, csr, offsets, counts, aggxbf, N);

  int nstrips = (N + 127) / 128;
  k_lin1m  <<<nstrips, 512, 0, stream>>>(aggxbf, xbf, W1c_bf, b1l, x1bf, N);
  k_agg2   <<<8192, 256, 0, stream>>>(x1bf, csr, offsets, counts, agg2bf, N);
  k_dual2  <<<nstrips, 512, 0, stream>>>(agg2bf, x1bf, W2l_bf, W2r_bf, b2l, x2bf, N);
  k_gru2   <<<nstrips, 512, 0, stream>>>(x2bf, h, Wih_bf, Whh_bf, bih, bhh, hnew, hnewbf, N);
  k_proj2  <<<nstrips, 512, 0, stream>>>(hnewbf, V2_bf, bd1, PQbf, D1, N);
  k_disp2  <<<1024, 256, 0, stream>>>(D1, Wd2, bd2, disp, N);
  k_force  <<<2048, 256, 0, stream>>>(ei, ea, PQbf, Wf1, bf1, Wf2, bf2, force, E);
}

// Round 12
// 283.401 us; speedup vs baseline: 1.0730x; 1.0730x over previous
//
#include <hip/hip_runtime.h>
#include <hip/hip_bf16.h>

#define H 128
#define IN_DIM 30
#define LDSP 136  // padded row stride (ushorts) for staged activations
#define LDSP1 72  // padded row stride for lin1 strips (K=64)

typedef __attribute__((ext_vector_type(8))) short bf16x8;
typedef __attribute__((ext_vector_type(8))) unsigned short u16x8;
typedef __attribute__((ext_vector_type(4))) float f32x4;

__device__ inline unsigned short f2bf(float f){
  unsigned int u = __builtin_bit_cast(unsigned int, f);
  unsigned int r = u + 0x7FFF + ((u >> 16) & 1);
  return (unsigned short)(r >> 16);
}
__device__ inline float bf2f(unsigned short b){
  unsigned int u = ((unsigned int)b) << 16;
  return __builtin_bit_cast(float, u);
}
__device__ inline bf16x8 ldfrag(const unsigned short* p){
  return *(const bf16x8*)p;
}

// ---------------- CSR build (XCD-partitioned: block b owns node range of partition b&7) ----------------
__global__ void k_count(const int* __restrict__ col, int* __restrict__ counts,
                        int E, int npp){
  int part = blockIdx.x & 7;
  int inst = blockIdx.x >> 3;
  int ninst = gridDim.x >> 3;
  int lo = part*npp, hi = lo + npp;
  for (int e = inst*blockDim.x + threadIdx.x; e < E; e += ninst*blockDim.x){
    int c = col[e];
    if (c >= lo && c < hi) atomicAdd(&counts[c], 1);
  }
}

__global__ void k_scanA(const int* __restrict__ counts, int* __restrict__ offsets,
                        int* __restrict__ bsum, int n){
  __shared__ int buf[256];
  int i = blockIdx.x*256 + threadIdx.x;
  int v = (i < n) ? counts[i] : 0;
  buf[threadIdx.x] = v; __syncthreads();
  for (int off = 1; off < 256; off <<= 1){
    int t = (threadIdx.x >= off) ? buf[threadIdx.x - off] : 0;
    __syncthreads();
    buf[threadIdx.x] += t;
    __syncthreads();
  }
  if (i < n) offsets[i] = buf[threadIdx.x] - v;
  if (threadIdx.x == 255) bsum[blockIdx.x] = buf[255];
}

__global__ void k_scanB(int* __restrict__ bsum, int nb){
  __shared__ int buf[256];
  int v = (threadIdx.x < nb) ? bsum[threadIdx.x] : 0;
  buf[threadIdx.x] = v; __syncthreads();
  for (int off = 1; off < 256; off <<= 1){
    int t = (threadIdx.x >= off) ? buf[threadIdx.x - off] : 0;
    __syncthreads();
    buf[threadIdx.x] += t;
    __syncthreads();
  }
  if (threadIdx.x < nb) bsum[threadIdx.x] = buf[threadIdx.x] - v;
}

__global__ void k_scanC(int* __restrict__ offsets, int* __restrict__ cursor,
                        const int* __restrict__ bsum, int n){
  int i = blockIdx.x*256 + threadIdx.x;
  if (i < n){ int o = offsets[i] + bsum[blockIdx.x]; offsets[i] = o; cursor[i] = o; }
}

__global__ void k_scatter(const int* __restrict__ ei, int* __restrict__ cursor,
                          int* __restrict__ csr, int E, int npp){
  int part = blockIdx.x & 7;
  int inst = blockIdx.x >> 3;
  int ninst = gridDim.x >> 3;
  int lo = part*npp, hi = lo + npp;
  for (int e = inst*blockDim.x + threadIdx.x; e < E; e += ninst*blockDim.x){
    int c = ei[E + e];
    if (c >= lo && c < hi){
      int p = atomicAdd(&cursor[c], 1);
      csr[p] = ei[e];
    }
  }
}

// ---------------- weight conversion to bf16 ----------------
// V2 layout [160][128]: rows 0..63 = Wf1 P-part, 64..127 = Wf1 Q-part, 128..159 = Wd1
// W1c layout [128][64]: cols 0..29 = W1l, 32..61 = W1r, rest 0
__global__ void k_wconv(const float* __restrict__ W2l, const float* __restrict__ W2r,
                        const float* __restrict__ Wih, const float* __restrict__ Whh,
                        const float* __restrict__ Wf1, const float* __restrict__ Wd1,
                        const float* __restrict__ W1l, const float* __restrict__ W1r,
                        unsigned short* __restrict__ W2l_bf, unsigned short* __restrict__ W2r_bf,
                        unsigned short* __restrict__ Wih_bf, unsigned short* __restrict__ Whh_bf,
                        unsigned short* __restrict__ V2_bf, unsigned short* __restrict__ W1c_bf){
  int stride = gridDim.x*blockDim.x;
  for (int i = blockIdx.x*blockDim.x + threadIdx.x; i < 49152; i += stride){
    if (i < 8192){
      int c = i >> 6, k = i & 63;
      float v = 0.f;
      if (k < IN_DIM)                      v = W1l[c*IN_DIM + k];
      else if (k >= 32 && k < 32 + IN_DIM) v = W1r[c*IN_DIM + (k - 32)];
      W1c_bf[i] = f2bf(v);
    }
    if (i < 16384){
      W2l_bf[i] = f2bf(W2l[i]);
      W2r_bf[i] = f2bf(W2r[i]);
    }
    if (i < 20480){
      int j = i >> 7, k = i & 127;
      float v;
      if (j < 64)        v = Wf1[j*260 + k];
      else if (j < 128)  v = Wf1[(j-64)*260 + 128 + k];
      else               v = Wd1[(j-128)*128 + k];
      V2_bf[i] = f2bf(v);
    }
    Wih_bf[i] = f2bf(Wih[i]);
    Whh_bf[i] = f2bf(Whh[i]);
  }
}

// ---------------- x f32 [N][30] -> bf16 [N][32] (padded) ----------------
__global__ void k_xconv(const float* __restrict__ x, unsigned short* __restrict__ xbf, int total){
  int stride = gridDim.x*blockDim.x;
  for (int i = blockIdx.x*blockDim.x + threadIdx.x; i < total; i += stride){
    int d = i >> 5, c = i & 31;
    xbf[i] = (c < IN_DIM) ? f2bf(x[(size_t)d*IN_DIM + c]) : (unsigned short)0;
  }
}

// ---------------- aggx: mean of x_bf rows; 4 neighbor-groups x 16 lanes/row ----------------
__global__ __launch_bounds__(256) void k_aggx(
    const unsigned short* __restrict__ xbf, const int* __restrict__ csr,
    const int* __restrict__ offsets, const int* __restrict__ counts,
    unsigned short* __restrict__ aggxbf, int N)
{
  int t = blockIdx.x*blockDim.x + threadIdx.x;
  int gw = t >> 6, lane = t & 63;
  int nw = (gridDim.x*blockDim.x) >> 6;
  int c2 = (lane & 15) << 1;  // 2 cols per lane
  int g  = lane >> 4;         // neighbor group 0..3
  for (int d = gw; d < N; d += nw){
    int base = offsets[d], cnt = counts[d];
    float a0 = 0.f, a1 = 0.f, b0 = 0.f, b1 = 0.f;
    int i = g;
    for (; i + 4 < cnt; i += 8){
      int s0 = csr[base + i];
      int s1 = csr[base + i + 4];
      unsigned int v0 = *(const unsigned int*)&xbf[(size_t)s0*32 + c2];
      unsigned int v1 = *(const unsigned int*)&xbf[(size_t)s1*32 + c2];
      a0 += bf2f((unsigned short)(v0 & 0xffff)); a1 += bf2f((unsigned short)(v0 >> 16));
      b0 += bf2f((unsigned short)(v1 & 0xffff)); b1 += bf2f((unsigned short)(v1 >> 16));
    }
    for (; i < cnt; i += 4){
      int s0 = csr[base + i];
      unsigned int v0 = *(const unsigned int*)&xbf[(size_t)s0*32 + c2];
      a0 += bf2f((unsigned short)(v0 & 0xffff)); a1 += bf2f((unsigned short)(v0 >> 16));
    }
    float s0_ = a0 + b0, s1_ = a1 + b1;
    s0_ += __shfl_xor(s0_, 16); s0_ += __shfl_xor(s0_, 32);
    s1_ += __shfl_xor(s1_, 16); s1_ += __shfl_xor(s1_, 32);
    if (lane < 16){
      float inv = 1.f / (float)(cnt > 0 ? cnt : 1);
      unsigned int o = (unsigned int)f2bf(s0_*inv) | ((unsigned int)f2bf(s1_*inv) << 16);
      *(unsigned int*)&aggxbf[(size_t)d*32 + c2] = o;
    }
  }
}

// ---------------- lin1 via MFMA strips: x1 = relu([agg|x] @ W1c.T + b1l) ----------------
__global__ __launch_bounds__(512) void k_lin1m(
    const unsigned short* __restrict__ aggxbf, const unsigned short* __restrict__ xbf,
    const unsigned short* __restrict__ W1c_bf, const float* __restrict__ b1l,
    unsigned short* __restrict__ x1bf, int N)
{
  __shared__ unsigned short sA[128*LDSP1];
  int tid = threadIdx.x;
  int wid = tid >> 6, l = tid & 63, m16 = l & 15, g4 = l >> 4;
  int col = wid*16 + m16;
  bf16x8 w1[2];
  #pragma unroll
  for (int kb = 0; kb < 2; kb++)
    w1[kb] = ldfrag(W1c_bf + (size_t)col*64 + kb*32 + g4*8);
  float bc = b1l[col];
  int nstrips = (N + 127) >> 7;
  for (int s = blockIdx.x; s < nstrips; s += gridDim.x){
    int base = s << 7;
    __syncthreads();
    for (int i = tid; i < 1024; i += 512){
      int row = i >> 3, c8 = (i & 7) << 3;
      int gr = min(base + row, N-1);
      u16x8 v;
      if (c8 < 32) v = *(const u16x8*)&aggxbf[(size_t)gr*32 + c8];
      else         v = *(const u16x8*)&xbf[(size_t)gr*32 + (c8 - 32)];
      *(u16x8*)&sA[row*LDSP1 + c8] = v;
    }
    __syncthreads();
    #pragma unroll 1
    for (int rt = 0; rt < 8; rt++){
      int rb = rt*16;
      f32x4 acc = {bc, bc, bc, bc};
      #pragma unroll
      for (int kb = 0; kb < 2; kb++){
        bf16x8 a = *(const bf16x8*)&sA[(rb + m16)*LDSP1 + kb*32 + g4*8];
        acc = __builtin_amdgcn_mfma_f32_16x16x32_bf16(a, w1[kb], acc, 0, 0, 0);
      }
      #pragma unroll
      for (int j = 0; j < 4; j++){
        int row = base + rb + g4*4 + j;
        if (row < N)
          x1bf[(size_t)row*H + col] = f2bf(fmaxf(acc[j], 0.f));
      }
    }
  }
}

// ---------------- agg2: mean of x1 rows; 4 neighbor-groups x 16 lanes/row ----------------
__global__ __launch_bounds__(256) void k_agg2(
    const unsigned short* __restrict__ x1bf, const int* __restrict__ csr,
    const int* __restrict__ offsets, const int* __restrict__ counts,
    unsigned short* __restrict__ agg2bf, int N)
{
  int t = blockIdx.x*blockDim.x + threadIdx.x;
  int gw = t >> 6, lane = t & 63;
  int nw = (gridDim.x*blockDim.x) >> 6;
  int c8 = (lane & 15) << 3;  // 8 cols per lane
  int g  = lane >> 4;         // neighbor group 0..3
  for (int d = gw; d < N; d += nw){
    int base = offsets[d], cnt = counts[d];
    float a[8] = {0.f,0.f,0.f,0.f,0.f,0.f,0.f,0.f};
    float b[8] = {0.f,0.f,0.f,0.f,0.f,0.f,0.f,0.f};
    int i = g;
    for (; i + 4 < cnt; i += 8){
      int s0 = csr[base + i];
      int s1 = csr[base + i + 4];
      u16x8 v0 = *(const u16x8*)&x1bf[(size_t)s0*H + c8];
      u16x8 v1 = *(const u16x8*)&x1bf[(size_t)s1*H + c8];
      #pragma unroll
      for (int j = 0; j < 8; j++){
        a[j] += bf2f(v0[j]);
        b[j] += bf2f(v1[j]);
      }
    }
    for (; i < cnt; i += 4){
      int s0 = csr[base + i];
      u16x8 v0 = *(const u16x8*)&x1bf[(size_t)s0*H + c8];
      #pragma unroll
      for (int j = 0; j < 8; j++) a[j] += bf2f(v0[j]);
    }
    float inv = 1.f / (float)(cnt > 0 ? cnt : 1);
    u16x8 o;
    #pragma unroll
    for (int j = 0; j < 8; j++){
      float s = a[j] + b[j];
      s += __shfl_xor(s, 16);
      s += __shfl_xor(s, 32);
      o[j] = f2bf(s*inv);
    }
    if (lane < 16)
      *(u16x8*)&agg2bf[(size_t)d*H + c8] = o;
  }
}

// ============ strip GEMM kernels: 512 thr, 128-row strips, LDS-staged A ============

// ---------------- SAGE2: x2 = relu(agg2@W2l.T + b2l + x1@W2r.T) ----------------
__global__ __launch_bounds__(512) void k_dual2(
    const unsigned short* __restrict__ Abf, const unsigned short* __restrict__ Bbf,
    const unsigned short* __restrict__ Wa, const unsigned short* __restrict__ Wb,
    const float* __restrict__ bias, unsigned short* __restrict__ outbf, int N)
{
  __shared__ unsigned short sA[128*LDSP];
  __shared__ unsigned short sB[128*LDSP];
  int tid = threadIdx.x;
  int wid = tid >> 6, l = tid & 63, m16 = l & 15, g4 = l >> 4;
  int col = wid*16 + m16;
  bf16x8 wa[4], wb[4];
  #pragma unroll
  for (int kb = 0; kb < 4; kb++){
    wa[kb] = ldfrag(Wa + (size_t)col*H + kb*32 + g4*8);
    wb[kb] = ldfrag(Wb + (size_t)col*H + kb*32 + g4*8);
  }
  float bc = bias[col];
  int nstrips = (N + 127) >> 7;
  for (int s = blockIdx.x; s < nstrips; s += gridDim.x){
    int base = s << 7;
    __syncthreads();
    for (int c = tid; c < 4096; c += 512){
      int mat = c >> 11, cc = c & 2047;
      int row = cc >> 4, co = cc & 15;
      int gr = min(base + row, N-1);
      u16x8 v = *(const u16x8*)((mat ? Bbf : Abf) + (size_t)gr*H + co*8);
      *(u16x8*)&((mat ? sB : sA)[row*LDSP + co*8]) = v;
    }
    __syncthreads();
    #pragma unroll 1
    for (int rt = 0; rt < 8; rt++){
      int rb = rt*16;
      f32x4 acc = {bc, bc, bc, bc};
      #pragma unroll
      for (int kb = 0; kb < 4; kb++){
        bf16x8 a = *(const bf16x8*)&sA[(rb + m16)*LDSP + kb*32 + g4*8];
        acc = __builtin_amdgcn_mfma_f32_16x16x32_bf16(a, wa[kb], acc, 0, 0, 0);
        bf16x8 b = *(const bf16x8*)&sB[(rb + m16)*LDSP + kb*32 + g4*8];
        acc = __builtin_amdgcn_mfma_f32_16x16x32_bf16(b, wb[kb], acc, 0, 0, 0);
      }
      #pragma unroll
      for (int j = 0; j < 4; j++){
        int row = base + rb + g4*4 + j;
        if (row < N)
          outbf[(size_t)row*H + col] = f2bf(fmaxf(acc[j], 0.f));
      }
    }
  }
}

// ---------------- fused GRU (stages h f32 -> bf16 inline) ----------------
__global__ __launch_bounds__(512) void k_gru2(
    const unsigned short* __restrict__ x2bf, const float* __restrict__ h,
    const unsigned short* __restrict__ Wih_bf, const unsigned short* __restrict__ Whh_bf,
    const float* __restrict__ bih, const float* __restrict__ bhh,
    float* __restrict__ hnew, unsigned short* __restrict__ hnewbf, int N)
{
  __shared__ unsigned short sX[128*LDSP];
  __shared__ unsigned short sH[128*LDSP];
  int tid = threadIdx.x;
  int wid = tid >> 6, l = tid & 63, m16 = l & 15, g4 = l >> 4;
  int col = wid*16 + m16;
  bf16x8 wih[3][4], whh[3][4];
  #pragma unroll
  for (int g = 0; g < 3; g++){
    #pragma unroll
    for (int kb = 0; kb < 4; kb++){
      wih[g][kb] = ldfrag(Wih_bf + (size_t)(g*H + col)*H + kb*32 + g4*8);
      whh[g][kb] = ldfrag(Whh_bf + (size_t)(g*H + col)*H + kb*32 + g4*8);
    }
  }
  float bir = bih[col],       bhr = bhh[col];
  float biz = bih[H + col],   bhz = bhh[H + col];
  float bin = bih[2*H + col], bhn = bhh[2*H + col];
  int nstrips = (N + 127) >> 7;
  for (int s = blockIdx.x; s < nstrips; s += gridDim.x){
    int base = s << 7;
    __syncthreads();
    for (int c = tid; c < 4096; c += 512){
      int mat = c >> 11, cc = c & 2047;
      int row = cc >> 4, co = cc & 15;
      int gr = min(base + row, N-1);
      if (mat == 0){
        u16x8 v = *(const u16x8*)(x2bf + (size_t)gr*H + co*8);
        *(u16x8*)&sX[row*LDSP + co*8] = v;
      } else {
        float4 f0 = *(const float4*)(h + (size_t)gr*H + co*8);
        float4 f1 = *(const float4*)(h + (size_t)gr*H + co*8 + 4);
        u16x8 v;
        v[0] = f2bf(f0.x); v[1] = f2bf(f0.y); v[2] = f2bf(f0.z); v[3] = f2bf(f0.w);
        v[4] = f2bf(f1.x); v[5] = f2bf(f1.y); v[6] = f2bf(f1.z); v[7] = f2bf(f1.w);
        *(u16x8*)&sH[row*LDSP + co*8] = v;
      }
    }
    __syncthreads();
    #pragma unroll 1
    for (int rt = 0; rt < 8; rt++){
      int rb = rt*16;
      bf16x8 aX[4], aH[4];
      #pragma unroll
      for (int kb = 0; kb < 4; kb++){
        aX[kb] = *(const bf16x8*)&sX[(rb + m16)*LDSP + kb*32 + g4*8];
        aH[kb] = *(const bf16x8*)&sH[(rb + m16)*LDSP + kb*32 + g4*8];
      }
      f32x4 aRi = {bir,bir,bir,bir}, aRh = {bhr,bhr,bhr,bhr};
      f32x4 aZi = {biz,biz,biz,biz}, aZh = {bhz,bhz,bhz,bhz};
      f32x4 aNi = {bin,bin,bin,bin}, aNh = {bhn,bhn,bhn,bhn};
      #pragma unroll
      for (int kb = 0; kb < 4; kb++){
        aRi = __builtin_amdgcn_mfma_f32_16x16x32_bf16(aX[kb], wih[0][kb], aRi, 0,0,0);
        aRh = __builtin_amdgcn_mfma_f32_16x16x32_bf16(aH[kb], whh[0][kb], aRh, 0,0,0);
        aZi = __builtin_amdgcn_mfma_f32_16x16x32_bf16(aX[kb], wih[1][kb], aZi, 0,0,0);
        aZh = __builtin_amdgcn_mfma_f32_16x16x32_bf16(aH[kb], whh[1][kb], aZh, 0,0,0);
        aNi = __builtin_amdgcn_mfma_f32_16x16x32_bf16(aX[kb], wih[2][kb], aNi, 0,0,0);
        aNh = __builtin_amdgcn_mfma_f32_16x16x32_bf16(aH[kb], whh[2][kb], aNh, 0,0,0);
      }
      #pragma unroll
      for (int j = 0; j < 4; j++){
        int row = base + rb + g4*4 + j;
        if (row < N){
          float r = 1.f / (1.f + expf(-(aRi[j] + aRh[j])));
          float z = 1.f / (1.f + expf(-(aZi[j] + aZh[j])));
          float nn = tanhf(aNi[j] + r*aNh[j]);
          float hv = bf2f(sH[(rb + g4*4 + j)*LDSP + col]);
          float o = (1.f - z)*nn + z*hv;
          hnew[(size_t)row*H + col] = o;
          hnewbf[(size_t)row*H + col] = f2bf(o);
        }
      }
    }
  }
}

// ---------------- proj: PQ (bf16, cols 0..127) and D1 (relu f32, V2 rows 128..159) ----------------
__global__ __launch_bounds__(512) void k_proj2(
    const unsigned short* __restrict__ hnewbf, const unsigned short* __restrict__ V2_bf,
    const float* __restrict__ bd1,
    unsigned short* __restrict__ PQbf, float* __restrict__ D1, int N)
{
  __shared__ unsigned short sHn[128*LDSP];
  int tid = threadIdx.x;
  int wid = tid >> 6, l = tid & 63, m16 = l & 15, g4 = l >> 4;
  int col = wid*16 + m16;
  bf16x8 v1[4], v2[4];
  #pragma unroll
  for (int kb = 0; kb < 4; kb++)
    v1[kb] = ldfrag(V2_bf + (size_t)col*H + kb*32 + g4*8);
  int dc = wid*16 + m16;
  float bdv = 0.f;
  if (wid < 2){
    #pragma unroll
    for (int kb = 0; kb < 4; kb++)
      v2[kb] = ldfrag(V2_bf + (size_t)(128 + dc)*H + kb*32 + g4*8);
    bdv = bd1[dc];
  }
  int nstrips = (N + 127) >> 7;
  for (int s = blockIdx.x; s < nstrips; s += gridDim.x){
    int base = s << 7;
    __syncthreads();
    for (int c = tid; c < 2048; c += 512){
      int row = c >> 4, co = c & 15;
      int gr = min(base + row, N-1);
      u16x8 v = *(const u16x8*)(hnewbf + (size_t)gr*H + co*8);
      *(u16x8*)&(sHn[row*LDSP + co*8]) = v;
    }
    __syncthreads();
    #pragma unroll 1
    for (int rt = 0; rt < 8; rt++){
      int rb = rt*16;
      bf16x8 aH[4];
      #pragma unroll
      for (int kb = 0; kb < 4; kb++)
        aH[kb] = *(const bf16x8*)&sHn[(rb + m16)*LDSP + kb*32 + g4*8];
      f32x4 acc = {0.f, 0.f, 0.f, 0.f};
      #pragma unroll
      for (int kb = 0; kb < 4; kb++)
        acc = __builtin_amdgcn_mfma_f32_16x16x32_bf16(aH[kb], v1[kb], acc, 0, 0, 0);
      #pragma unroll
      for (int j = 0; j < 4; j++){
        int row = base + rb + g4*4 + j;
        if (row < N)
          PQbf[(size_t)row*H + col] = f2bf(acc[j]);
      }
      if (wid < 2){
        f32x4 acc2 = {0.f, 0.f, 0.f, 0.f};
        #pragma unroll
        for (int kb = 0; kb < 4; kb++)
          acc2 = __builtin_amdgcn_mfma_f32_16x16x32_bf16(aH[kb], v2[kb], acc2, 0, 0, 0);
        #pragma unroll
        for (int j = 0; j < 4; j++){
          int row = base + rb + g4*4 + j;
          if (row < N)
            D1[(size_t)row*32 + dc] = fmaxf(acc2[j] + bdv, 0.f);
        }
      }
    }
  }
}

// ---------------- disp from D1: 32-lane group per node ----------------
__global__ __launch_bounds__(256) void k_disp2(
    const float* __restrict__ D1, const float* __restrict__ Wd2,
    const float* __restrict__ bd2, float* __restrict__ disp, int N)
{
  int t = blockIdx.x*blockDim.x + threadIdx.x;
  int gh = t >> 5, sub = t & 31;
  int nh = (gridDim.x*blockDim.x) >> 5;
  float w0 = Wd2[sub], w1 = Wd2[32 + sub], w2 = Wd2[64 + sub];
  float bo = (sub < 3) ? bd2[sub] : 0.f;
  for (int d = gh; d < N; d += nh){
    float v = D1[(size_t)d*32 + sub];
    float v0 = v*w0, v1 = v*w1, v2 = v*w2;
    #pragma unroll
    for (int off = 1; off < 32; off <<= 1){
      v0 += __shfl_xor(v0, off, 32);
      v1 += __shfl_xor(v1, off, 32);
      v2 += __shfl_xor(v2, off, 32);
    }
    if (sub < 3) disp[(size_t)d*3 + sub] = (sub == 0 ? v0 : (sub == 1 ? v1 : v2)) + bo;
  }
}

// ---------------- force decoder: MFMA over 16-edge tiles, 3-stage pipelined gathers ----------------
__global__ __launch_bounds__(256) void k_force(
    const int* __restrict__ ei, const float* __restrict__ ea,
    const unsigned short* __restrict__ PQbf,
    const float* __restrict__ Wf1, const float* __restrict__ bf1,
    const float* __restrict__ Wf2, const float* __restrict__ bf2,
    float* __restrict__ out, int E)
{
  int l = threadIdx.x & 63;
  int r = l & 15, g = l >> 4;
  float4 wc0[8], wc1[8];
  float b1r0[8], b1r1[8];
  bf16x8 bfr0, bfr1;
  float bo = (r < 3) ? bf2[r] : 0.f;
  #pragma unroll
  for (int j = 0; j < 8; j++){
    int k0 = g*8 + j, k1 = 32 + g*8 + j;
    wc0[j] = *(const float4*)&Wf1[k0*260 + 256];
    wc1[j] = *(const float4*)&Wf1[k1*260 + 256];
    b1r0[j] = bf1[k0];
    b1r1[j] = bf1[k1];
    bfr0[j] = (r < 3) ? (short)f2bf(Wf2[r*64 + k0]) : (short)0;
    bfr1[j] = (r < 3) ? (short)f2bf(Wf2[r*64 + k1]) : (short)0;
  }
  int nt = (E + 15) >> 4;
  int stride = gridDim.x*4;
  int t = blockIdx.x*4 + (threadIdx.x >> 6);
  if (t >= nt) return;

  int pcA = min(t*16 + r, E-1);
  int sA = ei[pcA], dA = ei[E + pcA];
  float4 aA = *(const float4*)&ea[(size_t)pcA*4];
  u16x8 pA0 = *(const u16x8*)&PQbf[(size_t)sA*H + g*8];
  u16x8 pA1 = *(const u16x8*)&PQbf[(size_t)sA*H + 32 + g*8];
  u16x8 qA0 = *(const u16x8*)&PQbf[(size_t)dA*H + 64 + g*8];
  u16x8 qA1 = *(const u16x8*)&PQbf[(size_t)dA*H + 96 + g*8];
  int t2 = t + stride;
  int sB = 0, dB = 0; float4 aB = {0.f,0.f,0.f,0.f};
  if (t2 < nt){
    int pcB = min(t2*16 + r, E-1);
    sB = ei[pcB]; dB = ei[E + pcB];
    aB = *(const float4*)&ea[(size_t)pcB*4];
  }
  while (true){
    u16x8 pB0, pB1, qB0, qB1;
    if (t2 < nt){
      pB0 = *(const u16x8*)&PQbf[(size_t)sB*H + g*8];
      pB1 = *(const u16x8*)&PQbf[(size_t)sB*H + 32 + g*8];
      qB0 = *(const u16x8*)&PQbf[(size_t)dB*H + 64 + g*8];
      qB1 = *(const u16x8*)&PQbf[(size_t)dB*H + 96 + g*8];
    }
    int t3 = t2 + stride;
    int sC = 0, dC = 0; float4 aC = {0.f,0.f,0.f,0.f};
    if (t3 < nt){
      int pcC = min(t3*16 + r, E-1);
      sC = ei[pcC]; dC = ei[E + pcC];
      aC = *(const float4*)&ea[(size_t)pcC*4];
    }
    {
      bf16x8 af0, af1;
      #pragma unroll
      for (int j = 0; j < 8; j++){
        float pre0 = bf2f((unsigned short)pA0[j]) + bf2f((unsigned short)qA0[j]) + b1r0[j]
                   + aA.x*wc0[j].x + aA.y*wc0[j].y + aA.z*wc0[j].z + aA.w*wc0[j].w;
        af0[j] = (short)f2bf(fmaxf(pre0, 0.f));
        float pre1 = bf2f((unsigned short)pA1[j]) + bf2f((unsigned short)qA1[j]) + b1r1[j]
                   + aA.x*wc1[j].x + aA.y*wc1[j].y + aA.z*wc1[j].z + aA.w*wc1[j].w;
        af1[j] = (short)f2bf(fmaxf(pre1, 0.f));
      }
      f32x4 acc = {0.f, 0.f, 0.f, 0.f};
      acc = __builtin_amdgcn_mfma_f32_16x16x32_bf16(af0, bfr0, acc, 0, 0, 0);
      acc = __builtin_amdgcn_mfma_f32_16x16x32_bf16(af1, bfr1, acc, 0, 0, 0);
      if (r < 3){
        #pragma unroll
        for (int j = 0; j < 4; j++){
          int erow = t*16 + g*4 + j;
          if (erow < E) out[(size_t)erow*3 + r] = acc[j] + bo;
        }
      }
    }
    if (t2 >= nt) break;
    t = t2; t2 = t3;
    aA = aB; pA0 = pB0; pA1 = pB1; qA0 = qB0; qA1 = qB1;
    sB = sC; dB = dC; aB = aC;
  }
}

extern "C" void kernel_launch(void* const* d_in, const int* in_sizes, int n_in,
                              void* d_out, int out_size, void* d_ws, size_t ws_size,
                              hipStream_t stream)
{
  const float* x   = (const float*)d_in[0];
  const int*   ei  = (const int*)d_in[1];
  const float* ea  = (const float*)d_in[2];
  const float* h   = (const float*)d_in[3];
  const float* W1l = (const float*)d_in[4];
  const float* b1l = (const float*)d_in[5];
  const float* W1r = (const float*)d_in[6];
  const float* W2l = (const float*)d_in[7];
  const float* b2l = (const float*)d_in[8];
  const float* W2r = (const float*)d_in[9];
  const float* Wih = (const float*)d_in[10];
  const float* Whh = (const float*)d_in[11];
  const float* bih = (const float*)d_in[12];
  const float* bhh = (const float*)d_in[13];
  const float* Wd1 = (const float*)d_in[14];
  const float* bd1 = (const float*)d_in[15];
  const float* Wd2 = (const float*)d_in[16];
  const float* bd2 = (const float*)d_in[17];
  const float* Wf1 = (const float*)d_in[18];
  const float* bf1 = (const float*)d_in[19];
  const float* Wf2 = (const float*)d_in[20];
  const float* bf2 = (const float*)d_in[21];

  int N = in_sizes[0] / IN_DIM;
  int E = in_sizes[1] / 2;
  int npp = (N + 7) / 8;  // nodes per XCD partition

  char* ws = (char*)d_ws;
  size_t off = 0;
  auto alloc = [&](size_t bytes) -> char* {
    char* p = ws + off;
    off = (off + bytes + 255) & ~(size_t)255;
    return p;
  };
  int* counts  = (int*)alloc((size_t)N*4);
  int* offsets = (int*)alloc((size_t)N*4);
  int* cursor  = (int*)alloc((size_t)N*4);
  int* bsum    = (int*)alloc(1024);
  int* csr     = (int*)alloc((size_t)E*4);
  // pool: aggxbf(uses 3.2MB of 6.4MB slot) | x1bf(12.8MB) | agg2bf(12.8MB);
  // reused post-GRU: PQbf (12.8MB) over aggx+x1bf slots; D1 (6.4MB) over agg2bf
  unsigned short* aggxbf = (unsigned short*)alloc((size_t)N*32*4);
  unsigned short* x1bf   = (unsigned short*)alloc((size_t)N*H*2);
  unsigned short* agg2bf = (unsigned short*)alloc((size_t)N*H*2);
  unsigned short* PQbf = (unsigned short*)aggxbf;
  float* D1            = (float*)agg2bf;
  unsigned short* x2bf   = (unsigned short*)alloc((size_t)N*H*2);
  unsigned short* hnewbf = (unsigned short*)alloc((size_t)N*H*2);
  unsigned short* xbf    = (unsigned short*)alloc((size_t)N*32*2);
  unsigned short* W2l_bf = (unsigned short*)alloc(16384*2);
  unsigned short* W2r_bf = (unsigned short*)alloc(16384*2);
  unsigned short* Wih_bf = (unsigned short*)alloc(49152*2);
  unsigned short* Whh_bf = (unsigned short*)alloc(49152*2);
  unsigned short* V2_bf  = (unsigned short*)alloc(20480*2);
  unsigned short* W1c_bf = (unsigned short*)alloc(8192*2);

  float* disp  = (float*)d_out;
  float* force = disp + (size_t)N*3;
  float* hnew  = force + (size_t)E*3;

  hipMemsetAsync(counts, 0, (size_t)N*4, stream);
  int nb = (N + 255) / 256;
  k_count  <<<2048, 256, 0, stream>>>(ei + E, counts, E, npp);
  k_scanA  <<<nb, 256, 0, stream>>>(counts, offsets, bsum, N);
  k_scanB  <<<1, 256, 0, stream>>>(bsum, nb);
  k_scanC  <<<nb, 256, 0, stream>>>(offsets, cursor, bsum, N);
  k_scatter<<<2048, 256, 0, stream>>>(ei, cursor, csr, E, npp);

  k_wconv  <<<192, 256, 0, stream>>>(W2l, W2r, Wih, Whh, Wf1, Wd1, W1l, W1r,
                                     W2l_bf, W2r_bf, Wih_bf, Whh_bf, V2_bf, W1c_bf);
  k_xconv  <<<1024, 256, 0, stream>>>(x, xbf, N*32);

  k_aggx   <<<4096, 256, 0, stream>>>(xbf, csr, offsets, counts, aggxbf, N);

  int nstrips = (N + 127) / 128;
  k_lin1m  <<<nstrips, 512, 0, stream>>>(aggxbf, xbf, W1c_bf, b1l, x1bf, N);
  k_agg2   <<<4096, 256, 0, stream>>>(x1bf, csr, offsets, counts, agg2bf, N);
  k_dual2  <<<nstrips, 512, 0, stream>>>(agg2bf, x1bf, W2l_bf, W2r_bf, b2l, x2bf, N);
  k_gru2   <<<nstrips, 512, 0, stream>>>(x2bf, h, Wih_bf, Whh_bf, bih, bhh, hnew, hnewbf, N);
  k_proj2  <<<nstrips, 512, 0, stream>>>(hnewbf, V2_bf, bd1, PQbf, D1, N);
  k_disp2  <<<1024, 256, 0, stream>>>(D1, Wd2, bd2, disp, N);
  k_force  <<<2048, 256, 0, stream>>>(ei, ea, PQbf, Wf1, bf1, Wf2, bf2, force, E);
}

// Round 13
// 272.783 us; speedup vs baseline: 1.1148x; 1.0389x over previous
//
#include <hip/hip_runtime.h>
#include <hip/hip_bf16.h>

#define H 128
#define IN_DIM 30
#define LDSP 136  // padded row stride (ushorts) for staged activations
#define LDSP1 72  // padded row stride for lin1 strips (K=64)

typedef __attribute__((ext_vector_type(8))) short bf16x8;
typedef __attribute__((ext_vector_type(8))) unsigned short u16x8;
typedef __attribute__((ext_vector_type(4))) float f32x4;

__device__ inline unsigned short f2bf(float f){
  unsigned int u = __builtin_bit_cast(unsigned int, f);
  unsigned int r = u + 0x7FFF + ((u >> 16) & 1);
  return (unsigned short)(r >> 16);
}
__device__ inline float bf2f(unsigned short b){
  unsigned int u = ((unsigned int)b) << 16;
  return __builtin_bit_cast(float, u);
}
__device__ inline bf16x8 ldfrag(const unsigned short* p){
  return *(const bf16x8*)p;
}

// ---------------- CSR build (XCD-partitioned: block b owns node range of partition b&7) ----------------
__global__ void k_count(const int* __restrict__ col, int* __restrict__ counts,
                        int E, int npp){
  int part = blockIdx.x & 7;
  int inst = blockIdx.x >> 3;
  int ninst = gridDim.x >> 3;
  int lo = part*npp, hi = lo + npp;
  for (int e = inst*blockDim.x + threadIdx.x; e < E; e += ninst*blockDim.x){
    int c = col[e];
    if (c >= lo && c < hi) atomicAdd(&counts[c], 1);
  }
}

__global__ void k_scanA(const int* __restrict__ counts, int* __restrict__ offsets,
                        int* __restrict__ bsum, int n){
  __shared__ int buf[256];
  int i = blockIdx.x*256 + threadIdx.x;
  int v = (i < n) ? counts[i] : 0;
  buf[threadIdx.x] = v; __syncthreads();
  for (int off = 1; off < 256; off <<= 1){
    int t = (threadIdx.x >= off) ? buf[threadIdx.x - off] : 0;
    __syncthreads();
    buf[threadIdx.x] += t;
    __syncthreads();
  }
  if (i < n) offsets[i] = buf[threadIdx.x] - v;
  if (threadIdx.x == 255) bsum[blockIdx.x] = buf[255];
}

__global__ void k_scanB(int* __restrict__ bsum, int nb){
  __shared__ int buf[256];
  int v = (threadIdx.x < nb) ? bsum[threadIdx.x] : 0;
  buf[threadIdx.x] = v; __syncthreads();
  for (int off = 1; off < 256; off <<= 1){
    int t = (threadIdx.x >= off) ? buf[threadIdx.x - off] : 0;
    __syncthreads();
    buf[threadIdx.x] += t;
    __syncthreads();
  }
  if (threadIdx.x < nb) bsum[threadIdx.x] = buf[threadIdx.x] - v;
}

__global__ void k_scanC(int* __restrict__ offsets, int* __restrict__ cursor,
                        const int* __restrict__ bsum, int n){
  int i = blockIdx.x*256 + threadIdx.x;
  if (i < n){ int o = offsets[i] + bsum[blockIdx.x]; offsets[i] = o; cursor[i] = o; }
}

__global__ void k_scatter(const int* __restrict__ ei, int* __restrict__ cursor,
                          int* __restrict__ csr, int E, int npp){
  int part = blockIdx.x & 7;
  int inst = blockIdx.x >> 3;
  int ninst = gridDim.x >> 3;
  int lo = part*npp, hi = lo + npp;
  for (int e = inst*blockDim.x + threadIdx.x; e < E; e += ninst*blockDim.x){
    int c = ei[E + e];
    if (c >= lo && c < hi){
      int p = atomicAdd(&cursor[c], 1);
      csr[p] = ei[e];
    }
  }
}

// ---------------- weight conversion to bf16 ----------------
// V2 layout [160][128]: rows 0..63 = Wf1 P-part, 64..127 = Wf1 Q-part, 128..159 = Wd1
// W1c layout [128][64]: cols 0..29 = W1l, 32..61 = W1r, rest 0
__global__ void k_wconv(const float* __restrict__ W2l, const float* __restrict__ W2r,
                        const float* __restrict__ Wih, const float* __restrict__ Whh,
                        const float* __restrict__ Wf1, const float* __restrict__ Wd1,
                        const float* __restrict__ W1l, const float* __restrict__ W1r,
                        unsigned short* __restrict__ W2l_bf, unsigned short* __restrict__ W2r_bf,
                        unsigned short* __restrict__ Wih_bf, unsigned short* __restrict__ Whh_bf,
                        unsigned short* __restrict__ V2_bf, unsigned short* __restrict__ W1c_bf){
  int stride = gridDim.x*blockDim.x;
  for (int i = blockIdx.x*blockDim.x + threadIdx.x; i < 49152; i += stride){
    if (i < 8192){
      int c = i >> 6, k = i & 63;
      float v = 0.f;
      if (k < IN_DIM)                      v = W1l[c*IN_DIM + k];
      else if (k >= 32 && k < 32 + IN_DIM) v = W1r[c*IN_DIM + (k - 32)];
      W1c_bf[i] = f2bf(v);
    }
    if (i < 16384){
      W2l_bf[i] = f2bf(W2l[i]);
      W2r_bf[i] = f2bf(W2r[i]);
    }
    if (i < 20480){
      int j = i >> 7, k = i & 127;
      float v;
      if (j < 64)        v = Wf1[j*260 + k];
      else if (j < 128)  v = Wf1[(j-64)*260 + 128 + k];
      else               v = Wd1[(j-128)*128 + k];
      V2_bf[i] = f2bf(v);
    }
    Wih_bf[i] = f2bf(Wih[i]);
    Whh_bf[i] = f2bf(Whh[i]);
  }
}

// ---------------- x f32 [N][30] -> bf16 [N][32] (padded) ----------------
__global__ void k_xconv(const float* __restrict__ x, unsigned short* __restrict__ xbf, int total){
  int stride = gridDim.x*blockDim.x;
  for (int i = blockIdx.x*blockDim.x + threadIdx.x; i < total; i += stride){
    int d = i >> 5, c = i & 31;
    xbf[i] = (c < IN_DIM) ? f2bf(x[(size_t)d*IN_DIM + c]) : (unsigned short)0;
  }
}

// ---------------- aggx: mean of x_bf rows; 4 neighbor-groups x 16 lanes/row ----------------
__global__ __launch_bounds__(256) void k_aggx(
    const unsigned short* __restrict__ xbf, const int* __restrict__ csr,
    const int* __restrict__ offsets, const int* __restrict__ counts,
    unsigned short* __restrict__ aggxbf, int N)
{
  int t = blockIdx.x*blockDim.x + threadIdx.x;
  int gw = t >> 6, lane = t & 63;
  int nw = (gridDim.x*blockDim.x) >> 6;
  int c2 = (lane & 15) << 1;  // 2 cols per lane
  int g  = lane >> 4;         // neighbor group 0..3
  for (int d = gw; d < N; d += nw){
    int base = offsets[d], cnt = counts[d];
    float a0 = 0.f, a1 = 0.f, b0 = 0.f, b1 = 0.f;
    int i = g;
    for (; i + 4 < cnt; i += 8){
      int s0 = csr[base + i];
      int s1 = csr[base + i + 4];
      unsigned int v0 = *(const unsigned int*)&xbf[(size_t)s0*32 + c2];
      unsigned int v1 = *(const unsigned int*)&xbf[(size_t)s1*32 + c2];
      a0 += bf2f((unsigned short)(v0 & 0xffff)); a1 += bf2f((unsigned short)(v0 >> 16));
      b0 += bf2f((unsigned short)(v1 & 0xffff)); b1 += bf2f((unsigned short)(v1 >> 16));
    }
    for (; i < cnt; i += 4){
      int s0 = csr[base + i];
      unsigned int v0 = *(const unsigned int*)&xbf[(size_t)s0*32 + c2];
      a0 += bf2f((unsigned short)(v0 & 0xffff)); a1 += bf2f((unsigned short)(v0 >> 16));
    }
    float s0_ = a0 + b0, s1_ = a1 + b1;
    s0_ += __shfl_xor(s0_, 16); s0_ += __shfl_xor(s0_, 32);
    s1_ += __shfl_xor(s1_, 16); s1_ += __shfl_xor(s1_, 32);
    if (lane < 16){
      float inv = 1.f / (float)(cnt > 0 ? cnt : 1);
      unsigned int o = (unsigned int)f2bf(s0_*inv) | ((unsigned int)f2bf(s1_*inv) << 16);
      *(unsigned int*)&aggxbf[(size_t)d*32 + c2] = o;
    }
  }
}

// ---------------- lin1 via MFMA strips: x1 = relu([agg|x] @ W1c.T + b1l) ----------------
__global__ __launch_bounds__(512) void k_lin1m(
    const unsigned short* __restrict__ aggxbf, const unsigned short* __restrict__ xbf,
    const unsigned short* __restrict__ W1c_bf, const float* __restrict__ b1l,
    unsigned short* __restrict__ x1bf, int N)
{
  __shared__ unsigned short sA[128*LDSP1];
  int tid = threadIdx.x;
  int wid = tid >> 6, l = tid & 63, m16 = l & 15, g4 = l >> 4;
  int col = wid*16 + m16;
  bf16x8 w1[2];
  #pragma unroll
  for (int kb = 0; kb < 2; kb++)
    w1[kb] = ldfrag(W1c_bf + (size_t)col*64 + kb*32 + g4*8);
  float bc = b1l[col];
  int nstrips = (N + 127) >> 7;
  for (int s = blockIdx.x; s < nstrips; s += gridDim.x){
    int base = s << 7;
    __syncthreads();
    for (int i = tid; i < 1024; i += 512){
      int row = i >> 3, c8 = (i & 7) << 3;
      int gr = min(base + row, N-1);
      u16x8 v;
      if (c8 < 32) v = *(const u16x8*)&aggxbf[(size_t)gr*32 + c8];
      else         v = *(const u16x8*)&xbf[(size_t)gr*32 + (c8 - 32)];
      *(u16x8*)&sA[row*LDSP1 + c8] = v;
    }
    __syncthreads();
    #pragma unroll 1
    for (int rt = 0; rt < 8; rt++){
      int rb = rt*16;
      f32x4 acc = {bc, bc, bc, bc};
      #pragma unroll
      for (int kb = 0; kb < 2; kb++){
        bf16x8 a = *(const bf16x8*)&sA[(rb + m16)*LDSP1 + kb*32 + g4*8];
        acc = __builtin_amdgcn_mfma_f32_16x16x32_bf16(a, w1[kb], acc, 0, 0, 0);
      }
      #pragma unroll
      for (int j = 0; j < 4; j++){
        int row = base + rb + g4*4 + j;
        if (row < N)
          x1bf[(size_t)row*H + col] = f2bf(fmaxf(acc[j], 0.f));
      }
    }
  }
}

// ---------------- agg2: mean of x1 rows; 4 neighbor-groups x 16 lanes/row ----------------
__global__ __launch_bounds__(256) void k_agg2(
    const unsigned short* __restrict__ x1bf, const int* __restrict__ csr,
    const int* __restrict__ offsets, const int* __restrict__ counts,
    unsigned short* __restrict__ agg2bf, int N)
{
  int t = blockIdx.x*blockDim.x + threadIdx.x;
  int gw = t >> 6, lane = t & 63;
  int nw = (gridDim.x*blockDim.x) >> 6;
  int c8 = (lane & 15) << 3;  // 8 cols per lane
  int g  = lane >> 4;         // neighbor group 0..3
  for (int d = gw; d < N; d += nw){
    int base = offsets[d], cnt = counts[d];
    float a[8] = {0.f,0.f,0.f,0.f,0.f,0.f,0.f,0.f};
    float b[8] = {0.f,0.f,0.f,0.f,0.f,0.f,0.f,0.f};
    int i = g;
    for (; i + 4 < cnt; i += 8){
      int s0 = csr[base + i];
      int s1 = csr[base + i + 4];
      u16x8 v0 = *(const u16x8*)&x1bf[(size_t)s0*H + c8];
      u16x8 v1 = *(const u16x8*)&x1bf[(size_t)s1*H + c8];
      #pragma unroll
      for (int j = 0; j < 8; j++){
        a[j] += bf2f(v0[j]);
        b[j] += bf2f(v1[j]);
      }
    }
    for (; i < cnt; i += 4){
      int s0 = csr[base + i];
      u16x8 v0 = *(const u16x8*)&x1bf[(size_t)s0*H + c8];
      #pragma unroll
      for (int j = 0; j < 8; j++) a[j] += bf2f(v0[j]);
    }
    float inv = 1.f / (float)(cnt > 0 ? cnt : 1);
    u16x8 o;
    #pragma unroll
    for (int j = 0; j < 8; j++){
      float s = a[j] + b[j];
      s += __shfl_xor(s, 16);
      s += __shfl_xor(s, 32);
      o[j] = f2bf(s*inv);
    }
    if (lane < 16)
      *(u16x8*)&agg2bf[(size_t)d*H + c8] = o;
  }
}

// ---------------- fused SAGE2 + GRU: x2 kept in LDS, never hits global ----------------
__global__ __launch_bounds__(512) void k_sage2gru(
    const unsigned short* __restrict__ agg2bf, const unsigned short* __restrict__ x1bf,
    const float* __restrict__ h,
    const unsigned short* __restrict__ W2l_bf, const unsigned short* __restrict__ W2r_bf,
    const float* __restrict__ b2l,
    const unsigned short* __restrict__ Wih_bf, const unsigned short* __restrict__ Whh_bf,
    const float* __restrict__ bih, const float* __restrict__ bhh,
    float* __restrict__ hnew, unsigned short* __restrict__ hnewbf, int N)
{
  __shared__ unsigned short sA[128*LDSP];  // agg2
  __shared__ unsigned short sB[128*LDSP];  // x1
  __shared__ unsigned short sH[128*LDSP];  // h (bf16)
  __shared__ unsigned short sX[128*LDSP];  // x2 (produced phase 1)
  int tid = threadIdx.x;
  int wid = tid >> 6, l = tid & 63, m16 = l & 15, g4 = l >> 4;
  int col = wid*16 + m16;
  bf16x8 wa[4], wb[4], wih[3][4], whh[3][4];
  #pragma unroll
  for (int kb = 0; kb < 4; kb++){
    wa[kb] = ldfrag(W2l_bf + (size_t)col*H + kb*32 + g4*8);
    wb[kb] = ldfrag(W2r_bf + (size_t)col*H + kb*32 + g4*8);
  }
  #pragma unroll
  for (int g = 0; g < 3; g++){
    #pragma unroll
    for (int kb = 0; kb < 4; kb++){
      wih[g][kb] = ldfrag(Wih_bf + (size_t)(g*H + col)*H + kb*32 + g4*8);
      whh[g][kb] = ldfrag(Whh_bf + (size_t)(g*H + col)*H + kb*32 + g4*8);
    }
  }
  float bc2 = b2l[col];
  float bir = bih[col],       bhr = bhh[col];
  float biz = bih[H + col],   bhz = bhh[H + col];
  float bin = bih[2*H + col], bhn = bhh[2*H + col];
  int nstrips = (N + 127) >> 7;
  for (int s = blockIdx.x; s < nstrips; s += gridDim.x){
    int base = s << 7;
    __syncthreads();
    for (int c = tid; c < 6144; c += 512){
      int mat = c >> 11, cc = c & 2047;
      int row = cc >> 4, co = cc & 15;
      int gr = min(base + row, N-1);
      if (mat == 0){
        u16x8 v = *(const u16x8*)(agg2bf + (size_t)gr*H + co*8);
        *(u16x8*)&sA[row*LDSP + co*8] = v;
      } else if (mat == 1){
        u16x8 v = *(const u16x8*)(x1bf + (size_t)gr*H + co*8);
        *(u16x8*)&sB[row*LDSP + co*8] = v;
      } else {
        float4 f0 = *(const float4*)(h + (size_t)gr*H + co*8);
        float4 f1 = *(const float4*)(h + (size_t)gr*H + co*8 + 4);
        u16x8 v;
        v[0] = f2bf(f0.x); v[1] = f2bf(f0.y); v[2] = f2bf(f0.z); v[3] = f2bf(f0.w);
        v[4] = f2bf(f1.x); v[5] = f2bf(f1.y); v[6] = f2bf(f1.z); v[7] = f2bf(f1.w);
        *(u16x8*)&sH[row*LDSP + co*8] = v;
      }
    }
    __syncthreads();
    // phase 1: x2 = relu(agg2@W2l.T + b2l + x1@W2r.T) -> sX (bf16)
    #pragma unroll 1
    for (int rt = 0; rt < 8; rt++){
      int rb = rt*16;
      f32x4 acc = {bc2, bc2, bc2, bc2};
      #pragma unroll
      for (int kb = 0; kb < 4; kb++){
        bf16x8 a = *(const bf16x8*)&sA[(rb + m16)*LDSP + kb*32 + g4*8];
        acc = __builtin_amdgcn_mfma_f32_16x16x32_bf16(a, wa[kb], acc, 0, 0, 0);
        bf16x8 b = *(const bf16x8*)&sB[(rb + m16)*LDSP + kb*32 + g4*8];
        acc = __builtin_amdgcn_mfma_f32_16x16x32_bf16(b, wb[kb], acc, 0, 0, 0);
      }
      #pragma unroll
      for (int j = 0; j < 4; j++)
        sX[(rb + g4*4 + j)*LDSP + col] = f2bf(fmaxf(acc[j], 0.f));
    }
    __syncthreads();
    // phase 2: GRU from sX, sH
    #pragma unroll 1
    for (int rt = 0; rt < 8; rt++){
      int rb = rt*16;
      bf16x8 aX[4], aH[4];
      #pragma unroll
      for (int kb = 0; kb < 4; kb++){
        aX[kb] = *(const bf16x8*)&sX[(rb + m16)*LDSP + kb*32 + g4*8];
        aH[kb] = *(const bf16x8*)&sH[(rb + m16)*LDSP + kb*32 + g4*8];
      }
      f32x4 aRi = {bir,bir,bir,bir}, aRh = {bhr,bhr,bhr,bhr};
      f32x4 aZi = {biz,biz,biz,biz}, aZh = {bhz,bhz,bhz,bhz};
      f32x4 aNi = {bin,bin,bin,bin}, aNh = {bhn,bhn,bhn,bhn};
      #pragma unroll
      for (int kb = 0; kb < 4; kb++){
        aRi = __builtin_amdgcn_mfma_f32_16x16x32_bf16(aX[kb], wih[0][kb], aRi, 0,0,0);
        aRh = __builtin_amdgcn_mfma_f32_16x16x32_bf16(aH[kb], whh[0][kb], aRh, 0,0,0);
        aZi = __builtin_amdgcn_mfma_f32_16x16x32_bf16(aX[kb], wih[1][kb], aZi, 0,0,0);
        aZh = __builtin_amdgcn_mfma_f32_16x16x32_bf16(aH[kb], whh[1][kb], aZh, 0,0,0);
        aNi = __builtin_amdgcn_mfma_f32_16x16x32_bf16(aX[kb], wih[2][kb], aNi, 0,0,0);
        aNh = __builtin_amdgcn_mfma_f32_16x16x32_bf16(aH[kb], whh[2][kb], aNh, 0,0,0);
      }
      #pragma unroll
      for (int j = 0; j < 4; j++){
        int row = base + rb + g4*4 + j;
        if (row < N){
          float r = 1.f / (1.f + expf(-(aRi[j] + aRh[j])));
          float z = 1.f / (1.f + expf(-(aZi[j] + aZh[j])));
          float nn = tanhf(aNi[j] + r*aNh[j]);
          float hv = bf2f(sH[(rb + g4*4 + j)*LDSP + col]);
          float o = (1.f - z)*nn + z*hv;
          hnew[(size_t)row*H + col] = o;
          hnewbf[(size_t)row*H + col] = f2bf(o);
        }
      }
    }
  }
}

// ---------------- proj + disp: PQ (bf16) out; D1 -> LDS -> disp in-kernel ----------------
__global__ __launch_bounds__(512) void k_proj2(
    const unsigned short* __restrict__ hnewbf, const unsigned short* __restrict__ V2_bf,
    const float* __restrict__ bd1, const float* __restrict__ Wd2,
    const float* __restrict__ bd2,
    unsigned short* __restrict__ PQbf, float* __restrict__ disp, int N)
{
  __shared__ unsigned short sHn[128*LDSP];
  __shared__ float sD1[128*33];
  int tid = threadIdx.x;
  int wid = tid >> 6, l = tid & 63, m16 = l & 15, g4 = l >> 4;
  int col = wid*16 + m16;
  bf16x8 v1[4], v2[4];
  #pragma unroll
  for (int kb = 0; kb < 4; kb++)
    v1[kb] = ldfrag(V2_bf + (size_t)col*H + kb*32 + g4*8);
  int dc = wid*16 + m16;
  float bdv = 0.f;
  if (wid < 2){
    #pragma unroll
    for (int kb = 0; kb < 4; kb++)
      v2[kb] = ldfrag(V2_bf + (size_t)(128 + dc)*H + kb*32 + g4*8);
    bdv = bd1[dc];
  }
  // disp-phase per-thread constants: row = tid>>2, cols q*8..q*8+7
  int q = tid & 3;
  float wd0[8], wd1c[8], wd2c[8];
  #pragma unroll
  for (int i = 0; i < 8; i++){
    int c = q*8 + i;
    wd0[i] = Wd2[c]; wd1c[i] = Wd2[32 + c]; wd2c[i] = Wd2[64 + c];
  }
  float bo0 = bd2[0], bo1 = bd2[1], bo2 = bd2[2];
  int nstrips = (N + 127) >> 7;
  for (int s = blockIdx.x; s < nstrips; s += gridDim.x){
    int base = s << 7;
    __syncthreads();
    for (int c = tid; c < 2048; c += 512){
      int row = c >> 4, co = c & 15;
      int gr = min(base + row, N-1);
      u16x8 v = *(const u16x8*)(hnewbf + (size_t)gr*H + co*8);
      *(u16x8*)&(sHn[row*LDSP + co*8]) = v;
    }
    __syncthreads();
    #pragma unroll 1
    for (int rt = 0; rt < 8; rt++){
      int rb = rt*16;
      bf16x8 aH[4];
      #pragma unroll
      for (int kb = 0; kb < 4; kb++)
        aH[kb] = *(const bf16x8*)&sHn[(rb + m16)*LDSP + kb*32 + g4*8];
      f32x4 acc = {0.f, 0.f, 0.f, 0.f};
      #pragma unroll
      for (int kb = 0; kb < 4; kb++)
        acc = __builtin_amdgcn_mfma_f32_16x16x32_bf16(aH[kb], v1[kb], acc, 0, 0, 0);
      #pragma unroll
      for (int j = 0; j < 4; j++){
        int row = base + rb + g4*4 + j;
        if (row < N)
          PQbf[(size_t)row*H + col] = f2bf(acc[j]);
      }
      if (wid < 2){
        f32x4 acc2 = {0.f, 0.f, 0.f, 0.f};
        #pragma unroll
        for (int kb = 0; kb < 4; kb++)
          acc2 = __builtin_amdgcn_mfma_f32_16x16x32_bf16(aH[kb], v2[kb], acc2, 0, 0, 0);
        #pragma unroll
        for (int j = 0; j < 4; j++)
          sD1[(rb + g4*4 + j)*33 + dc] = fmaxf(acc2[j] + bdv, 0.f);
      }
    }
    __syncthreads();
    // disp: 4 threads per row, 8 cols each, 2-step shuffle reduce
    {
      int row = tid >> 2;
      const float* dr = &sD1[row*33 + q*8];
      float v0 = 0.f, v1_ = 0.f, v2_ = 0.f;
      #pragma unroll
      for (int i = 0; i < 8; i++){
        float d1 = dr[i];
        v0 += d1*wd0[i]; v1_ += d1*wd1c[i]; v2_ += d1*wd2c[i];
      }
      v0 += __shfl_xor(v0, 1);  v0 += __shfl_xor(v0, 2);
      v1_ += __shfl_xor(v1_, 1); v1_ += __shfl_xor(v1_, 2);
      v2_ += __shfl_xor(v2_, 1); v2_ += __shfl_xor(v2_, 2);
      int grow = base + row;
      if (q == 0 && grow < N){
        disp[(size_t)grow*3 + 0] = v0 + bo0;
        disp[(size_t)grow*3 + 1] = v1_ + bo1;
        disp[(size_t)grow*3 + 2] = v2_ + bo2;
      }
    }
  }
}

// ---------------- force decoder: MFMA over 16-edge tiles, 3-stage pipelined gathers ----------------
__global__ __launch_bounds__(256) void k_force(
    const int* __restrict__ ei, const float* __restrict__ ea,
    const unsigned short* __restrict__ PQbf,
    const float* __restrict__ Wf1, const float* __restrict__ bf1,
    const float* __restrict__ Wf2, const float* __restrict__ bf2,
    float* __restrict__ out, int E)
{
  int l = threadIdx.x & 63;
  int r = l & 15, g = l >> 4;
  float4 wc0[8], wc1[8];
  float b1r0[8], b1r1[8];
  bf16x8 bfr0, bfr1;
  float bo = (r < 3) ? bf2[r] : 0.f;
  #pragma unroll
  for (int j = 0; j < 8; j++){
    int k0 = g*8 + j, k1 = 32 + g*8 + j;
    wc0[j] = *(const float4*)&Wf1[k0*260 + 256];
    wc1[j] = *(const float4*)&Wf1[k1*260 + 256];
    b1r0[j] = bf1[k0];
    b1r1[j] = bf1[k1];
    bfr0[j] = (r < 3) ? (short)f2bf(Wf2[r*64 + k0]) : (short)0;
    bfr1[j] = (r < 3) ? (short)f2bf(Wf2[r*64 + k1]) : (short)0;
  }
  int nt = (E + 15) >> 4;
  int stride = gridDim.x*4;
  int t = blockIdx.x*4 + (threadIdx.x >> 6);
  if (t >= nt) return;

  int pcA = min(t*16 + r, E-1);
  int sA = ei[pcA], dA = ei[E + pcA];
  float4 aA = *(const float4*)&ea[(size_t)pcA*4];
  u16x8 pA0 = *(const u16x8*)&PQbf[(size_t)sA*H + g*8];
  u16x8 pA1 = *(const u16x8*)&PQbf[(size_t)sA*H + 32 + g*8];
  u16x8 qA0 = *(const u16x8*)&PQbf[(size_t)dA*H + 64 + g*8];
  u16x8 qA1 = *(const u16x8*)&PQbf[(size_t)dA*H + 96 + g*8];
  int t2 = t + stride;
  int sB = 0, dB = 0; float4 aB = {0.f,0.f,0.f,0.f};
  if (t2 < nt){
    int pcB = min(t2*16 + r, E-1);
    sB = ei[pcB]; dB = ei[E + pcB];
    aB = *(const float4*)&ea[(size_t)pcB*4];
  }
  while (true){
    u16x8 pB0, pB1, qB0, qB1;
    if (t2 < nt){
      pB0 = *(const u16x8*)&PQbf[(size_t)sB*H + g*8];
      pB1 = *(const u16x8*)&PQbf[(size_t)sB*H + 32 + g*8];
      qB0 = *(const u16x8*)&PQbf[(size_t)dB*H + 64 + g*8];
      qB1 = *(const u16x8*)&PQbf[(size_t)dB*H + 96 + g*8];
    }
    int t3 = t2 + stride;
    int sC = 0, dC = 0; float4 aC = {0.f,0.f,0.f,0.f};
    if (t3 < nt){
      int pcC = min(t3*16 + r, E-1);
      sC = ei[pcC]; dC = ei[E + pcC];
      aC = *(const float4*)&ea[(size_t)pcC*4];
    }
    {
      bf16x8 af0, af1;
      #pragma unroll
      for (int j = 0; j < 8; j++){
        float pre0 = bf2f((unsigned short)pA0[j]) + bf2f((unsigned short)qA0[j]) + b1r0[j]
                   + aA.x*wc0[j].x + aA.y*wc0[j].y + aA.z*wc0[j].z + aA.w*wc0[j].w;
        af0[j] = (short)f2bf(fmaxf(pre0, 0.f));
        float pre1 = bf2f((unsigned short)pA1[j]) + bf2f((unsigned short)qA1[j]) + b1r1[j]
                   + aA.x*wc1[j].x + aA.y*wc1[j].y + aA.z*wc1[j].z + aA.w*wc1[j].w;
        af1[j] = (short)f2bf(fmaxf(pre1, 0.f));
      }
      f32x4 acc = {0.f, 0.f, 0.f, 0.f};
      acc = __builtin_amdgcn_mfma_f32_16x16x32_bf16(af0, bfr0, acc, 0, 0, 0);
      acc = __builtin_amdgcn_mfma_f32_16x16x32_bf16(af1, bfr1, acc, 0, 0, 0);
      if (r < 3){
        #pragma unroll
        for (int j = 0; j < 4; j++){
          int erow = t*16 + g*4 + j;
          if (erow < E) out[(size_t)erow*3 + r] = acc[j] + bo;
        }
      }
    }
    if (t2 >= nt) break;
    t = t2; t2 = t3;
    aA = aB; pA0 = pB0; pA1 = pB1; qA0 = qB0; qA1 = qB1;
    sB = sC; dB = dC; aB = aC;
  }
}

extern "C" void kernel_launch(void* const* d_in, const int* in_sizes, int n_in,
                              void* d_out, int out_size, void* d_ws, size_t ws_size,
                              hipStream_t stream)
{
  const float* x   = (const float*)d_in[0];
  const int*   ei  = (const int*)d_in[1];
  const float* ea  = (const float*)d_in[2];
  const float* h   = (const float*)d_in[3];
  const float* W1l = (const float*)d_in[4];
  const float* b1l = (const float*)d_in[5];
  const float* W1r = (const float*)d_in[6];
  const float* W2l = (const float*)d_in[7];
  const float* b2l = (const float*)d_in[8];
  const float* W2r = (const float*)d_in[9];
  const float* Wih = (const float*)d_in[10];
  const float* Whh = (const float*)d_in[11];
  const float* bih = (const float*)d_in[12];
  const float* bhh = (const float*)d_in[13];
  const float* Wd1 = (const float*)d_in[14];
  const float* bd1 = (const float*)d_in[15];
  const float* Wd2 = (const float*)d_in[16];
  const float* bd2 = (const float*)d_in[17];
  const float* Wf1 = (const float*)d_in[18];
  const float* bf1 = (const float*)d_in[19];
  const float* Wf2 = (const float*)d_in[20];
  const float* bf2 = (const float*)d_in[21];

  int N = in_sizes[0] / IN_DIM;
  int E = in_sizes[1] / 2;
  int npp = (N + 7) / 8;  // nodes per XCD partition

  char* ws = (char*)d_ws;
  size_t off = 0;
  auto alloc = [&](size_t bytes) -> char* {
    char* p = ws + off;
    off = (off + bytes + 255) & ~(size_t)255;
    return p;
  };
  int* counts  = (int*)alloc((size_t)N*4);
  int* offsets = (int*)alloc((size_t)N*4);
  int* cursor  = (int*)alloc((size_t)N*4);
  int* bsum    = (int*)alloc(1024);
  int* csr     = (int*)alloc((size_t)E*4);
  // pool: aggxbf(3.2MB of 6.4MB slot) | x1bf(12.8MB) | agg2bf(12.8MB);
  // reused post-GRU: PQbf (12.8MB) over aggx+x1bf slots
  unsigned short* aggxbf = (unsigned short*)alloc((size_t)N*32*4);
  unsigned short* x1bf   = (unsigned short*)alloc((size_t)N*H*2);
  unsigned short* agg2bf = (unsigned short*)alloc((size_t)N*H*2);
  unsigned short* PQbf = (unsigned short*)aggxbf;
  unsigned short* hnewbf = (unsigned short*)alloc((size_t)N*H*2);
  unsigned short* xbf    = (unsigned short*)alloc((size_t)N*32*2);
  unsigned short* W2l_bf = (unsigned short*)alloc(16384*2);
  unsigned short* W2r_bf = (unsigned short*)alloc(16384*2);
  unsigned short* Wih_bf = (unsigned short*)alloc(49152*2);
  unsigned short* Whh_bf = (unsigned short*)alloc(49152*2);
  unsigned short* V2_bf  = (unsigned short*)alloc(20480*2);
  unsigned short* W1c_bf = (unsigned short*)alloc(8192*2);

  float* disp  = (float*)d_out;
  float* force = disp + (size_t)N*3;
  float* hnew  = force + (size_t)E*3;

  hipMemsetAsync(counts, 0, (size_t)N*4, stream);
  int nb = (N + 255) / 256;
  k_count  <<<2048, 256, 0, stream>>>(ei + E, counts, E, npp);
  k_scanA  <<<nb, 256, 0, stream>>>(counts, offsets, bsum, N);
  k_scanB  <<<1, 256, 0, stream>>>(bsum, nb);
  k_scanC  <<<nb, 256, 0, stream>>>(offsets, cursor, bsum, N);
  k_scatter<<<2048, 256, 0, stream>>>(ei, cursor, csr, E, npp);

  k_wconv  <<<192, 256, 0, stream>>>(W2l, W2r, Wih, Whh, Wf1, Wd1, W1l, W1r,
                                     W2l_bf, W2r_bf, Wih_bf, Whh_bf, V2_bf, W1c_bf);
  k_xconv  <<<1024, 256, 0, stream>>>(x, xbf, N*32);

  k_aggx   <<<4096, 256, 0, stream>>>(xbf, csr, offsets, counts, aggxbf, N);

  int nstrips = (N + 127) / 128;
  k_lin1m  <<<nstrips, 512, 0, stream>>>(aggxbf, xbf, W1c_bf, b1l, x1bf, N);
  k_agg2   <<<4096, 256, 0, stream>>>(x1bf, csr, offsets, counts, agg2bf, N);
  k_sage2gru<<<nstrips, 512, 0, stream>>>(agg2bf, x1bf, h, W2l_bf, W2r_bf, b2l,
                                          Wih_bf, Whh_bf, bih, bhh, hnew, hnewbf, N);
  k_proj2  <<<nstrips, 512, 0, stream>>>(hnewbf, V2_bf, bd1, Wd2, bd2, PQbf, disp, N);
  k_force  <<<2048, 256, 0, stream>>>(ei, ea, PQbf, Wf1, bf1, Wf2, bf2, force, E);
}